// Round 4
// baseline (226.664 us; speedup 1.0000x reference)
//
#include <hip/hip_runtime.h>
#include <stdint.h>

typedef unsigned short u16;
typedef __attribute__((ext_vector_type(8))) short s16x8;
typedef __attribute__((ext_vector_type(4))) float f32x4;

#define MFMA_BF16(a, b, c) __builtin_amdgcn_mfma_f32_16x16x32_bf16((a), (b), (c), 0, 0, 0)

typedef const __attribute__((address_space(1))) uint32_t* gas1_t;
typedef __attribute__((address_space(3))) uint32_t* las3_t;
#define GLDS16(dst, src) __builtin_amdgcn_global_load_lds((gas1_t)(src), (las3_t)(dst), 16, 0, 0)

static __device__ __forceinline__ u16 f2bf(float f) {
    uint32_t u = __float_as_uint(f);
    u = (u + 0x7fffu + ((u >> 16) & 1u)) >> 16;
    return (u16)u;
}
static __device__ __forceinline__ uint32_t pk2bf(float a, float b) {
    return (uint32_t)f2bf(a) | ((uint32_t)f2bf(b) << 16);
}

// ---------------- f32 -> bf16 linear convert (x) ----------------
__global__ void k_cvt_bf16(const float* __restrict__ in, u16* __restrict__ out) {
    int i = (blockIdx.x * 256 + threadIdx.x) * 8;
    f32x4 a = *(const f32x4*)(in + i);
    f32x4 b = *(const f32x4*)(in + i + 4);
    s16x8 r;
    r[0] = (short)f2bf(a[0]); r[1] = (short)f2bf(a[1]);
    r[2] = (short)f2bf(a[2]); r[3] = (short)f2bf(a[3]);
    r[4] = (short)f2bf(b[0]); r[5] = (short)f2bf(b[1]);
    r[6] = (short)f2bf(b[2]); r[7] = (short)f2bf(b[3]);
    *(s16x8*)(out + i) = r;
}

// ---------------- W [k][n] f32 -> Wt [n][k] bf16 (768x768, 4 weights) ----------------
__global__ void k_transpose_w(const float* __restrict__ w0, const float* __restrict__ w1,
                              const float* __restrict__ w2, const float* __restrict__ w3,
                              u16* __restrict__ t0, u16* __restrict__ t1,
                              u16* __restrict__ t2, u16* __restrict__ t3) {
    __shared__ float tile[32][33];
    const float* W; u16* T;
    switch (blockIdx.z) {
        case 0:  W = w0; T = t0; break;
        case 1:  W = w1; T = t1; break;
        case 2:  W = w2; T = t2; break;
        default: W = w3; T = t3; break;
    }
    int n0 = blockIdx.x * 32, k0 = blockIdx.y * 32;
    int tx = threadIdx.x, ty = threadIdx.y;
#pragma unroll
    for (int i = 0; i < 4; ++i)
        tile[ty + 8 * i][tx] = W[(size_t)(k0 + ty + 8 * i) * 768 + n0 + tx];
    __syncthreads();
#pragma unroll
    for (int i = 0; i < 4; ++i)
        T[(size_t)(n0 + ty + 8 * i) * 768 + k0 + tx] = f2bf(tile[tx][ty + 8 * i]);
}

// ---------------- 128x128-tile bf16 GEMM (m97 structure) ----------------
// MODE 0: grid (18,32), bx -> sel(0=Q,1=K,2=V), 6 n-tiles. Q scaled by C2.
//         sel 0/1 scatter [bh][s][64]; sel 2 scatters V^T [bh][64][s].
// MODE 1: grid (6,32), Bt=btq, bias=bq, f32 out (out-projection).
template <int MODE>
__global__ __launch_bounds__(256) void k_gemm128(
        const u16* __restrict__ A,
        const u16* __restrict__ btq, const u16* __restrict__ btk, const u16* __restrict__ btv,
        const float* __restrict__ bq, const float* __restrict__ bk, const float* __restrict__ bv,
        u16* __restrict__ outq, u16* __restrict__ outk, u16* __restrict__ outv,
        float* __restrict__ outf) {
    __shared__ u16 lA[128 * 64];
    __shared__ u16 lB[128 * 64];
    int sel, nb;
    const u16* Bt; const float* bias;
    if (MODE == 0) {
        sel = blockIdx.x / 6; nb = blockIdx.x % 6;
        if (sel == 0)      { Bt = btq; bias = bq; }
        else if (sel == 1) { Bt = btk; bias = bk; }
        else               { Bt = btv; bias = bv; }
    } else {
        sel = 0; nb = blockIdx.x; Bt = btq; bias = bq;
    }
    const int t = threadIdx.x, lane = t & 63, w = t >> 6;
    const int wr = w >> 1, wc = w & 1;
    const int c = lane & 15, g = lane >> 4;
    const int m0 = blockIdx.y * 128, n0 = nb * 128;
    f32x4 acc[4][4] = {};
    // staging: linear LDS dest, pre-swizzled global source (granule ^ (row&7))
    const int srow = 8 * w + (lane >> 3);                 // 0..31 within an issue
    const int scol = 8 * ((lane & 7) ^ ((lane >> 3) & 7));
    const u16* gA = A  + (size_t)(m0 + srow) * 768 + scol;
    const u16* gB = Bt + (size_t)(n0 + srow) * 768 + scol;
    for (int kb = 0; kb < 768; kb += 64) {
#pragma unroll
        for (int j = 0; j < 4; ++j) {
            GLDS16(&lA[j * 2048 + w * 512], gA + (size_t)j * 32 * 768 + kb);
            GLDS16(&lB[j * 2048 + w * 512], gB + (size_t)j * 32 * 768 + kb);
        }
        __syncthreads();   // drains vmcnt (global_load_lds)
#pragma unroll
        for (int kh = 0; kh < 2; ++kh) {
            s16x8 af[4], bf[4];
            const int gg = kh * 4 + g;
#pragma unroll
            for (int i = 0; i < 4; ++i) {
                int ra = wr * 64 + i * 16 + c;
                af[i] = *(const s16x8*)&lA[ra * 64 + 8 * (gg ^ (ra & 7))];
                int rb = wc * 64 + i * 16 + c;
                bf[i] = *(const s16x8*)&lB[rb * 64 + 8 * (gg ^ (rb & 7))];
            }
#pragma unroll
            for (int i = 0; i < 4; ++i)
#pragma unroll
                for (int j = 0; j < 4; ++j)
                    acc[i][j] = MFMA_BF16(af[i], bf[j], acc[i][j]);
        }
        __syncthreads();
    }
    const float C2 = 0.18033688011112042f;  // (1/8)*log2(e), folded into Q
    if (MODE == 1) {
#pragma unroll
        for (int i = 0; i < 4; ++i)
#pragma unroll
            for (int j = 0; j < 4; ++j) {
                const int n = n0 + wc * 64 + j * 16 + c;
                const float bvv = bias[n];
#pragma unroll
                for (int rr = 0; rr < 4; ++rr) {
                    const int m = m0 + wr * 64 + i * 16 + g * 4 + rr;
                    outf[(size_t)m * 768 + n] = acc[i][j][rr] + bvv;
                }
            }
    } else if (sel < 2) {   // Q/K: [bh][s][hd], Q pre-scaled by C2
        u16* outp = (sel == 0) ? outq : outk;
        const float osc = (sel == 0) ? C2 : 1.0f;
#pragma unroll
        for (int i = 0; i < 4; ++i)
#pragma unroll
            for (int j = 0; j < 4; ++j) {
                const int n = n0 + wc * 64 + j * 16 + c;
                const int h = n >> 6, hd = n & 63;
                const float bvv = bias[n];
#pragma unroll
                for (int rr = 0; rr < 4; ++rr) {
                    const int m = m0 + wr * 64 + i * 16 + g * 4 + rr;
                    const int b = m >> 11, s = m & 2047;
                    outp[(((size_t)(b * 12 + h) * 2048 + s) << 6) + hd] =
                        f2bf((acc[i][j][rr] + bvv) * osc);
                }
            }
    } else {                // V^T: [bh][hd][s], 4 consecutive s packed
#pragma unroll
        for (int i = 0; i < 4; ++i)
#pragma unroll
            for (int j = 0; j < 4; ++j) {
                const int n = n0 + wc * 64 + j * 16 + c;
                const int h = n >> 6, hd = n & 63;
                const float bvv = bias[n];
                const int m = m0 + wr * 64 + i * 16 + g * 4;
                const int b = m >> 11, s = m & 2047;
                uint64_t pk = (uint64_t)pk2bf(acc[i][j][0] + bvv, acc[i][j][1] + bvv) |
                              ((uint64_t)pk2bf(acc[i][j][2] + bvv, acc[i][j][3] + bvv) << 32);
                *(uint64_t*)&outv[((size_t)(b * 12 + h) * 64 + hd) * 2048 + s] = pk;
            }
    }
}

// ---------------- causal flash attention: split-K, 4 waves / 16-row q-tile ----------------
// grid 3072 x 256thr. Wave w handles chunks w, w+4, ... of 64 keys; LDS combine at end.
__global__ __launch_bounds__(256, 4) void k_attn(const u16* __restrict__ qw,
                                                 const u16* __restrict__ kw,
                                                 const u16* __restrict__ vt,
                                                 u16* __restrict__ ctxb) {
    __shared__ float smem[4224];       // P: 4x1088 u16 (8704B) overlaps combine cc[4][16][64]+m+s
    u16* lPa = (u16*)smem;
    const int bid = blockIdx.x;
    const int qt = 127 - bid / 24;     // big tiles dispatch first
    const int bh = bid % 24;
    const int t = threadIdx.x, lane = t & 63, w = t >> 6;
    const int c = lane & 15, g = lane >> 4;
    const int q0 = qt * 16;
    const u16* qp = qw + (size_t)bh * 2048 * 64;
    const u16* kp = kw + (size_t)bh * 2048 * 64;
    const u16* vp = vt + (size_t)bh * 64 * 2048;
    const s16x8 qf0 = *(const s16x8*)&qp[(size_t)(q0 + c) * 64 + g * 8];
    const s16x8 qf1 = *(const s16x8*)&qp[(size_t)(q0 + c) * 64 + 32 + g * 8];
    f32x4 ctx[4] = {};                 // ctx^T: [hd=s4*16+4g+rr][q=c]
    float m2 = -1e30f, ssum = 0.0f;    // ssum = per-lane partial (g-reduced at end)
    const int nk = q0 + 16, NC = (nk + 63) >> 6;
    u16* Pw = lPa + w * 1088;          // 16*68 u16 per wave
    for (int ci = w; ci < NC; ci += 4) {
        const int Kc = ci * 64;
        // ---- QK^T (Q pre-scaled): S^T[key][q] ----
        f32x4 sv[4];
#pragma unroll
        for (int u = 0; u < 4; ++u) {
            const u16* krow = kp + (size_t)(Kc + u * 16 + c) * 64;
            s16x8 k0 = *(const s16x8*)(krow + g * 8);
            s16x8 k1 = *(const s16x8*)(krow + 32 + g * 8);
            f32x4 a = {0.f, 0.f, 0.f, 0.f};
            a = MFMA_BF16(k0, qf0, a);
            a = MFMA_BF16(k1, qf1, a);
            sv[u] = a;
        }
        // ---- prefetch V frags (used after softmax) ----
        s16x8 vfr[2][4];
#pragma unroll
        for (int h2 = 0; h2 < 2; ++h2)
#pragma unroll
            for (int s4 = 0; s4 < 4; ++s4)
                vfr[h2][s4] = *(const s16x8*)&vp[(size_t)(s4 * 16 + c) * 2048 + Kc + h2 * 32 + g * 8];
        // ---- mask (diagonal chunk only) ----
        float tv[16];
        if (Kc + 63 <= q0) {
#pragma unroll
            for (int i = 0; i < 16; ++i) tv[i] = sv[i >> 2][i & 3];
        } else {
            const int qg = q0 + c;
#pragma unroll
            for (int u = 0; u < 4; ++u)
#pragma unroll
                for (int rr = 0; rr < 4; ++rr) {
                    const int key = Kc + u * 16 + 4 * g + rr;
                    tv[u * 4 + rr] = (key <= qg) ? sv[u][rr] : -1e30f;
                }
        }
        // ---- defer-max online softmax: no cross-lane ops in steady state ----
        float mt = tv[0];
#pragma unroll
        for (int i = 1; i < 16; ++i) mt = fmaxf(mt, tv[i]);
        if (!__all(mt <= m2 + 8.0f)) {
            float mq = fmaxf(mt, __shfl_xor(mt, 16));
            mq = fmaxf(mq, __shfl_xor(mq, 32));
            const float mnew = fmaxf(m2, mq);
            const float fac = __builtin_amdgcn_exp2f(m2 - mnew);
            ssum *= fac;
#pragma unroll
            for (int s4 = 0; s4 < 4; ++s4) ctx[s4] *= fac;
            m2 = mnew;
        }
        float p[16];
#pragma unroll
        for (int i = 0; i < 16; ++i) { p[i] = __builtin_amdgcn_exp2f(tv[i] - m2); ssum += p[i]; }
        // ---- pack P (cvt_pk), LDS roundtrip into PV B-frag layout ----
        uint32_t pk[8];
#pragma unroll
        for (int i = 0; i < 8; ++i)
            asm volatile("v_cvt_pk_bf16_f32 %0, %1, %2"
                         : "=v"(pk[i]) : "v"(p[2 * i]), "v"(p[2 * i + 1]));
#pragma unroll
        for (int u = 0; u < 4; ++u) {
            uint64_t q64 = (uint64_t)pk[2 * u] | ((uint64_t)pk[2 * u + 1] << 32);
            *(uint64_t*)&Pw[c * 68 + u * 16 + 4 * g] = q64;
        }
        asm volatile("s_waitcnt lgkmcnt(0)" ::: "memory");
#pragma unroll
        for (int h2 = 0; h2 < 2; ++h2) {
            s16x8 pf = *(const s16x8*)&Pw[c * 68 + h2 * 32 + 8 * g];
#pragma unroll
            for (int s4 = 0; s4 < 4; ++s4)
                ctx[s4] = MFMA_BF16(vfr[h2][s4], pf, ctx[s4]);   // ctx^T += V^T·P^T
        }
        asm volatile("" ::: "memory");
    }
    // ---- cross-wave combine ----
    ssum += __shfl_xor(ssum, 16);
    ssum += __shfl_xor(ssum, 32);
    __syncthreads();                    // P region dead; safe to overwrite with cc
    float* cc   = smem;                 // [w][16][64]
    float* marr = smem + 4096;          // [w][16]
    float* sarr = smem + 4160;          // [w][16]
#pragma unroll
    for (int s4 = 0; s4 < 4; ++s4)
#pragma unroll
        for (int rr = 0; rr < 4; ++rr)
            cc[(w * 16 + s4 * 4 + rr) * 64 + lane] = ctx[s4][rr];
    if (g == 0) { marr[w * 16 + c] = m2; sarr[w * 16 + c] = ssum; }
    __syncthreads();
    const float mw0 = marr[c], mw1 = marr[16 + c], mw2 = marr[32 + c], mw3 = marr[48 + c];
    const float mstar = fmaxf(fmaxf(mw0, mw1), fmaxf(mw2, mw3));
    const float sc0 = __builtin_amdgcn_exp2f(mw0 - mstar);
    const float sc1 = __builtin_amdgcn_exp2f(mw1 - mstar);
    const float sc2 = __builtin_amdgcn_exp2f(mw2 - mstar);
    const float sc3 = __builtin_amdgcn_exp2f(mw3 - mstar);
    const float st = sc0 * sarr[c] + sc1 * sarr[16 + c] + sc2 * sarr[32 + c] + sc3 * sarr[48 + c];
    const float inv = 1.0f / st;
    float ov[4];
#pragma unroll
    for (int rr = 0; rr < 4; ++rr) {
        const int idx = (w * 4 + rr) * 64 + lane;
        float v = sc0 * cc[idx] + sc1 * cc[1024 + idx] + sc2 * cc[2048 + idx] + sc3 * cc[3072 + idx];
        ov[rr] = v * inv;
    }
    const int b = bh / 12, h = bh - b * 12;
    const size_t rowbase = (size_t)(b * 2048 + q0 + c) * 768 + h * 64;
    uint64_t opk = (uint64_t)pk2bf(ov[0], ov[1]) | ((uint64_t)pk2bf(ov[2], ov[3]) << 32);
    *(uint64_t*)&ctxb[rowbase + w * 16 + 4 * g] = opk;
}

// ---------------- launch ----------------
extern "C" void kernel_launch(void* const* d_in, const int* in_sizes, int n_in,
                              void* d_out, int out_size, void* d_ws, size_t ws_size,
                              hipStream_t stream) {
    (void)in_sizes; (void)n_in; (void)out_size; (void)ws_size;
    const float* x  = (const float*)d_in[0];
    const float* Wq = (const float*)d_in[1];
    const float* bq = (const float*)d_in[2];
    const float* Wk = (const float*)d_in[3];
    const float* bk = (const float*)d_in[4];
    const float* Wv = (const float*)d_in[5];
    const float* bv = (const float*)d_in[6];
    const float* Wo = (const float*)d_in[7];
    const float* bo = (const float*)d_in[8];
    char* ws = (char*)d_ws;
    u16* xb   = (u16*)(ws);               // 4096*768 bf16      = 6291456 B
    u16* wqt  = (u16*)(ws + 6291456);     // 768*768 bf16 (W^T) = 1179648 B
    u16* wkt  = (u16*)(ws + 7471104);
    u16* wvt  = (u16*)(ws + 8650752);
    u16* wot  = (u16*)(ws + 9830400);
    u16* qwv  = (u16*)(ws + 11010048);    // [24][2048][64] bf16 (Q pre-scaled)
    u16* kwv  = (u16*)(ws + 17301504);
    u16* vtw  = (u16*)(ws + 23592960);    // V^T [24][64][2048] bf16
    u16* ctx  = (u16*)(ws + 29884416);    // [4096][768] bf16
    float* out = (float*)d_out;

    k_cvt_bf16<<<1536, 256, 0, stream>>>(x, xb);
    k_transpose_w<<<dim3(24, 24, 4), dim3(32, 8), 0, stream>>>(Wq, Wk, Wv, Wo, wqt, wkt, wvt, wot);
    k_gemm128<0><<<dim3(18, 32), 256, 0, stream>>>(xb, wqt, wkt, wvt, bq, bk, bv,
                                                   qwv, kwv, vtw, nullptr);
    k_attn<<<3072, 256, 0, stream>>>(qwv, kwv, vtw, ctx);
    k_gemm128<1><<<dim3(6, 32), 256, 0, stream>>>(ctx, wot, nullptr, nullptr, bo, nullptr, nullptr,
                                                  nullptr, nullptr, nullptr, out);
}

// Round 5
// 199.108 us; speedup vs baseline: 1.1384x; 1.1384x over previous
//
#include <hip/hip_runtime.h>
#include <stdint.h>

typedef unsigned short u16;
typedef __attribute__((ext_vector_type(8))) short s16x8;
typedef __attribute__((ext_vector_type(4))) float f32x4;
typedef __attribute__((ext_vector_type(16))) float f32x16;

#define MFMA_BF16(a, b, c) __builtin_amdgcn_mfma_f32_16x16x32_bf16((a), (b), (c), 0, 0, 0)
#define MFMA32(a, b, c) __builtin_amdgcn_mfma_f32_32x32x16_bf16((a), (b), (c), 0, 0, 0)

typedef const __attribute__((address_space(1))) uint32_t* gas1_t;
typedef __attribute__((address_space(3))) uint32_t* las3_t;
#define GLDS16(dst, src) __builtin_amdgcn_global_load_lds((gas1_t)(src), (las3_t)(dst), 16, 0, 0)

static __device__ __forceinline__ u16 f2bf(float f) {
    uint32_t u = __float_as_uint(f);
    u = (u + 0x7fffu + ((u >> 16) & 1u)) >> 16;
    return (u16)u;
}
static __device__ __forceinline__ uint32_t pk2bf(float a, float b) {
    return (uint32_t)f2bf(a) | ((uint32_t)f2bf(b) << 16);
}

// ---------------- f32 -> bf16 linear convert (x) ----------------
__global__ void k_cvt_bf16(const float* __restrict__ in, u16* __restrict__ out) {
    int i = (blockIdx.x * 256 + threadIdx.x) * 8;
    f32x4 a = *(const f32x4*)(in + i);
    f32x4 b = *(const f32x4*)(in + i + 4);
    s16x8 r;
    r[0] = (short)f2bf(a[0]); r[1] = (short)f2bf(a[1]);
    r[2] = (short)f2bf(a[2]); r[3] = (short)f2bf(a[3]);
    r[4] = (short)f2bf(b[0]); r[5] = (short)f2bf(b[1]);
    r[6] = (short)f2bf(b[2]); r[7] = (short)f2bf(b[3]);
    *(s16x8*)(out + i) = r;
}

// ---------------- W [k][n] f32 -> Wt [n][k] bf16 (768x768, 4 weights) ----------------
__global__ void k_transpose_w(const float* __restrict__ w0, const float* __restrict__ w1,
                              const float* __restrict__ w2, const float* __restrict__ w3,
                              u16* __restrict__ t0, u16* __restrict__ t1,
                              u16* __restrict__ t2, u16* __restrict__ t3) {
    __shared__ float tile[32][33];
    const float* W; u16* T;
    switch (blockIdx.z) {
        case 0:  W = w0; T = t0; break;
        case 1:  W = w1; T = t1; break;
        case 2:  W = w2; T = t2; break;
        default: W = w3; T = t3; break;
    }
    int n0 = blockIdx.x * 32, k0 = blockIdx.y * 32;
    int tx = threadIdx.x, ty = threadIdx.y;
#pragma unroll
    for (int i = 0; i < 4; ++i)
        tile[ty + 8 * i][tx] = W[(size_t)(k0 + ty + 8 * i) * 768 + n0 + tx];
    __syncthreads();
#pragma unroll
    for (int i = 0; i < 4; ++i)
        T[(size_t)(n0 + ty + 8 * i) * 768 + k0 + tx] = f2bf(tile[tx][ty + 8 * i]);
}

// ---------------- 128x128-tile bf16 GEMM, LDS-transposed coalesced epilogue ----------
// MODE 0: grid (18,32), bx -> sel(0=Q,1=K,2=V). Q scaled by C2.
//         sel 0/1 -> [bh][s][64] bf16 ; sel 2 -> V^T [bh][64][s] bf16.
// MODE 1: grid (6,32), Bt=btq, bias=bq, f32 out[m][768] (out-projection).
template <int MODE>
__global__ __launch_bounds__(256) void k_gemm128(
        const u16* __restrict__ A,
        const u16* __restrict__ btq, const u16* __restrict__ btk, const u16* __restrict__ btv,
        const float* __restrict__ bq, const float* __restrict__ bk, const float* __restrict__ bv,
        u16* __restrict__ outq, u16* __restrict__ outk, u16* __restrict__ outv,
        float* __restrict__ outf) {
    __shared__ __align__(16) char ldsb[32768];
    u16* lA = (u16*)ldsb;
    u16* lB = (u16*)(ldsb + 16384);
    int sel, nb;
    const u16* Bt; const float* bias;
    if (MODE == 0) {
        sel = blockIdx.x / 6; nb = blockIdx.x % 6;
        if (sel == 0)      { Bt = btq; bias = bq; }
        else if (sel == 1) { Bt = btk; bias = bk; }
        else               { Bt = btv; bias = bv; }
    } else {
        sel = 0; nb = blockIdx.x; Bt = btq; bias = bq;
    }
    const int t = threadIdx.x, lane = t & 63, w = t >> 6;
    const int wr = w >> 1, wc = w & 1;
    const int c = lane & 15, g = lane >> 4;
    const int m0 = blockIdx.y * 128, n0 = nb * 128;
    f32x4 acc[4][4] = {};
    const int srow = 8 * w + (lane >> 3);
    const int scol = 8 * ((lane & 7) ^ ((lane >> 3) & 7));
    const u16* gA = A  + (size_t)(m0 + srow) * 768 + scol;
    const u16* gB = Bt + (size_t)(n0 + srow) * 768 + scol;
    for (int kb = 0; kb < 768; kb += 64) {
#pragma unroll
        for (int j = 0; j < 4; ++j) {
            GLDS16(&lA[j * 2048 + w * 512], gA + (size_t)j * 32 * 768 + kb);
            GLDS16(&lB[j * 2048 + w * 512], gB + (size_t)j * 32 * 768 + kb);
        }
        __syncthreads();
#pragma unroll
        for (int kh = 0; kh < 2; ++kh) {
            s16x8 af[4], bf[4];
            const int gg = kh * 4 + g;
#pragma unroll
            for (int i = 0; i < 4; ++i) {
                int ra = wr * 64 + i * 16 + c;
                af[i] = *(const s16x8*)&lA[ra * 64 + 8 * (gg ^ (ra & 7))];
                int rb = wc * 64 + i * 16 + c;
                bf[i] = *(const s16x8*)&lB[rb * 64 + 8 * (gg ^ (rb & 7))];
            }
#pragma unroll
            for (int i = 0; i < 4; ++i)
#pragma unroll
                for (int j = 0; j < 4; ++j)
                    acc[i][j] = MFMA_BF16(af[i], bf[j], acc[i][j]);
        }
        __syncthreads();
    }
    const float C2 = 0.18033688011112042f;  // (1/8)*log2(e), folded into Q
    float* lC = (float*)ldsb;
    const float osc = (MODE == 0 && sel == 0) ? C2 : 1.0f;
#pragma unroll
    for (int j4 = 0; j4 < 4; ++j4) {
        // write phase: waves with wc == j4>>1 own cols [j4*32, j4*32+32)
        if (wc == (j4 >> 1)) {
#pragma unroll
            for (int jj = 0; jj < 2; ++jj) {
                const int j = (j4 & 1) * 2 + jj;
                const int n = n0 + wc * 64 + j * 16 + c;
                const float bvv = bias[n];
                const int colb = (j * 16 + c) & 31;
#pragma unroll
                for (int i = 0; i < 4; ++i)
#pragma unroll
                    for (int rr = 0; rr < 4; ++rr) {
                        const int m = wr * 64 + i * 16 + g * 4 + rr;
                        const float v = (acc[i][j][rr] + bvv) * osc;
                        if (MODE == 0 && sel == 2) lC[colb * 130 + m] = v;   // [32][130]
                        else                       lC[m * 34 + colb] = v;   // [128][34]
                    }
            }
        }
        __syncthreads();
        // read phase: coalesced wide stores
        if (MODE == 1) {
#pragma unroll
            for (int it = 0; it < 2; ++it) {
                const int p = t + it * 256, sl = p >> 2, cb = (p & 3) * 8;
                f32x4 v0, v1;
#pragma unroll
                for (int e = 0; e < 4; ++e) { v0[e] = lC[sl * 34 + cb + e]; v1[e] = lC[sl * 34 + cb + 4 + e]; }
                float* op = outf + (size_t)(m0 + sl) * 768 + n0 + j4 * 32 + cb;
                *(f32x4*)op = v0; *(f32x4*)(op + 4) = v1;
            }
        } else if (sel < 2) {
            u16* outp = (sel == 0) ? outq : outk;
#pragma unroll
            for (int it = 0; it < 2; ++it) {
                const int p = t + it * 256, sl = p >> 2, cb = (p & 3) * 8;
                s16x8 ov;
#pragma unroll
                for (int e = 0; e < 8; ++e) ov[e] = (short)f2bf(lC[sl * 34 + cb + e]);
                const int ng = n0 + j4 * 32 + cb, hh = ng >> 6, hd = ng & 63;
                const int m = m0 + sl, bb = m >> 11, ss = m & 2047;
                *(s16x8*)&outp[(((size_t)(bb * 12 + hh) * 2048 + ss) << 6) + hd] = ov;
            }
        } else {
#pragma unroll
            for (int it = 0; it < 2; ++it) {
                const int p = t + it * 256, nn = p >> 4, mb = (p & 15) * 8;
                s16x8 ov;
#pragma unroll
                for (int e = 0; e < 8; ++e) ov[e] = (short)f2bf(lC[nn * 130 + mb + e]);
                const int ng = n0 + j4 * 32 + nn, hh = ng >> 6, hd = ng & 63;
                const int bb = m0 >> 11, ss = (m0 & 2047) + mb;
                *(s16x8*)&outv[((size_t)(bb * 12 + hh) * 64 + hd) * 2048 + ss] = ov;
            }
        }
        __syncthreads();
    }
}

// ---------------- causal flash attention: 4 waves x 32 q-rows, 32x32 MFMA ----------------
// grid = 24*16 = 384 blocks x 256 thr, descending-work order.
// K/V double-buffered in LDS via global_load_lds; counted vmcnt(4) + raw s_barrier.
// Softmax in-register (swapped QK^T); P -> B-frag via cvt_pk + one shfl_xor(32).
__global__ __launch_bounds__(256) void k_attn(const u16* __restrict__ qw,
                                              const u16* __restrict__ kw,
                                              const u16* __restrict__ vt,
                                              u16* __restrict__ ctxb) {
    __shared__ u16 lK[2][64 * 64];   // [key][hd], XOR-swizzled (granule ^ row&7)
    __shared__ u16 lV[2][64 * 64];   // V^T [hd][key], same swizzle
    const int bid = blockIdx.x;
    const int qt = 15 - bid / 24;    // heavy tiles first
    const int bh = bid % 24;
    const int t = threadIdx.x, lane = t & 63, w = t >> 6;
    const int l31 = lane & 31, hi = lane >> 5;
    const int q0w = qt * 128 + w * 32;
    const u16* qp = qw + (size_t)bh * 2048 * 64;
    const u16* kp = kw + (size_t)bh * 2048 * 64;
    const u16* vp = vt + (size_t)bh * 64 * 2048;
    // Q B-frags (scaled by C2 already): col=q=l31, k=d
    s16x8 qf[4];
#pragma unroll
    for (int dk = 0; dk < 4; ++dk)
        qf[dk] = *(const s16x8*)&qp[(size_t)(q0w + l31) * 64 + dk * 16 + hi * 8];
    asm volatile("s_waitcnt vmcnt(0)" ::: "memory");   // clean vm queue before staging
    // staging addresses: 4 GLDS16 per lane per chunk (2 K rows-of-8, 2 V rows-of-8)
    const int lr = lane >> 3, lg = lane & 7;
    const int swz8 = 8 * (lg ^ lr);
    const u16* kpb = kp + (size_t)(w * 16 + lr) * 64 + swz8;
    const u16* vpb = vp + (size_t)(w * 16 + lr) * 2048 + swz8;
    const int NC = 2 * qt + 2;
    const int lastq = q0w + 31;
    f32x16 ct[2] = {};               // ctx^T [hd-tile][reg]: col=q, row=hd
    float m2 = -1e30f, ssum = 0.0f;
#define STAGE(bf, ch)                                                          \
    {                                                                          \
        const u16* ks_ = kpb + (size_t)(ch) * 4096;                            \
        GLDS16(&lK[bf][(w * 16) * 64], ks_);                                   \
        GLDS16(&lK[bf][(w * 16 + 8) * 64], ks_ + 512);                         \
        const u16* vs_ = vpb + (size_t)(ch) * 64;                              \
        GLDS16(&lV[bf][(w * 16) * 64], vs_);                                   \
        GLDS16(&lV[bf][(w * 16 + 8) * 64], vs_ + 8 * 2048);                    \
    }
    STAGE(0, 0);
    for (int ch = 0; ch < NC; ++ch) {
        const int bf = ch & 1, Kc = ch * 64;
        if (ch + 1 < NC) {
            STAGE(bf ^ 1, ch + 1);
            asm volatile("s_waitcnt vmcnt(4)" ::: "memory");   // cur buffer landed
        } else {
            asm volatile("s_waitcnt vmcnt(0)" ::: "memory");
        }
        __builtin_amdgcn_sched_barrier(0);
        __builtin_amdgcn_s_barrier();
        if (Kc <= lastq) {           // wave-uniform causal skip
            // ---- QK^T: S^T[key][q], two 32-key tiles ----
            f32x16 st[2] = {};
#pragma unroll
            for (int dk = 0; dk < 4; ++dk) {
                const int gr = dk * 2 + hi;
                const int r0 = l31, r1 = 32 + l31;
                s16x8 kf0 = *(const s16x8*)&lK[bf][r0 * 64 + 8 * (gr ^ (r0 & 7))];
                s16x8 kf1 = *(const s16x8*)&lK[bf][r1 * 64 + 8 * (gr ^ (r1 & 7))];
                st[0] = MFMA32(kf0, qf[dk], st[0]);
                st[1] = MFMA32(kf1, qf[dk], st[1]);
            }
            // ---- mask (one diagonal chunk per wave) ----
            const int qg = q0w + l31;
            float tv[32];
            if (Kc + 63 <= q0w) {
#pragma unroll
                for (int j = 0; j < 16; ++j) { tv[j] = st[0][j]; tv[16 + j] = st[1][j]; }
            } else {
                const int kb = Kc + 4 * hi;
#pragma unroll
                for (int j = 0; j < 16; ++j) {
                    const int kloc = (j & 3) + 8 * (j >> 2);
                    tv[j]      = (kb + kloc      <= qg) ? st[0][j] : -1e30f;
                    tv[16 + j] = (kb + kloc + 32 <= qg) ? st[1][j] : -1e30f;
                }
            }
            // ---- defer-max online softmax (no cross-lane in steady state) ----
            float mt = tv[0];
#pragma unroll
            for (int j = 1; j < 32; ++j) mt = fmaxf(mt, tv[j]);
            if (!__all(mt <= m2 + 8.0f)) {
                float mq = fmaxf(mt, __shfl_xor(mt, 32));
                const float mnew = fmaxf(m2, mq);
                const float fac = __builtin_amdgcn_exp2f(m2 - mnew);
                ssum *= fac;
#pragma unroll
                for (int j = 0; j < 16; ++j) { ct[0][j] *= fac; ct[1][j] *= fac; }
                m2 = mnew;
            }
            float p[32];
#pragma unroll
            for (int j = 0; j < 32; ++j) { p[j] = __builtin_amdgcn_exp2f(tv[j] - m2); ssum += p[j]; }
            // ---- P -> bf16 B-frags in-register; PV ----
#pragma unroll
            for (int kt = 0; kt < 2; ++kt) {
                uint32_t pcv[8];
#pragma unroll
                for (int x = 0; x < 8; ++x) {
                    const int j = kt * 16 + 4 * (x >> 1) + 2 * (x & 1);
                    asm volatile("v_cvt_pk_bf16_f32 %0, %1, %2"
                                 : "=v"(pcv[x]) : "v"(p[j]), "v"(p[j + 1]));
                }
#pragma unroll
                for (int kl = 0; kl < 2; ++kl) {
                    const uint32_t s0 = hi ? pcv[4 * kl]     : pcv[4 * kl + 2];
                    const uint32_t s1 = hi ? pcv[4 * kl + 1] : pcv[4 * kl + 3];
                    const uint32_t r0 = __shfl_xor(s0, 32);
                    const uint32_t r1 = __shfl_xor(s1, 32);
                    union { uint32_t u[4]; s16x8 v; } pf;
                    pf.u[0] = hi ? r0 : pcv[4 * kl];
                    pf.u[1] = hi ? r1 : pcv[4 * kl + 1];
                    pf.u[2] = hi ? pcv[4 * kl + 2] : r0;
                    pf.u[3] = hi ? pcv[4 * kl + 3] : r1;
                    const int gr = (kt * 2 + kl) * 2 + hi;
                    const int rv0 = l31, rv1 = 32 + l31;
                    s16x8 vf0 = *(const s16x8*)&lV[bf][rv0 * 64 + 8 * (gr ^ (rv0 & 7))];
                    s16x8 vf1 = *(const s16x8*)&lV[bf][rv1 * 64 + 8 * (gr ^ (rv1 & 7))];
                    ct[0] = MFMA32(vf0, pf.v, ct[0]);
                    ct[1] = MFMA32(vf1, pf.v, ct[1]);
                }
            }
        }
        __builtin_amdgcn_s_barrier();
    }
    // ---- finalize ----
    ssum += __shfl_xor(ssum, 32);
    const float inv = 1.0f / ssum;
    const int b = bh / 12, h = bh - b * 12;
    const size_t base = (size_t)(b * 2048 + q0w + l31) * 768 + h * 64;
#pragma unroll
    for (int ht = 0; ht < 2; ++ht)
#pragma unroll
        for (int a = 0; a < 4; ++a) {
            const int hd = ht * 32 + 8 * a + 4 * hi;
            uint64_t pk = (uint64_t)pk2bf(ct[ht][4 * a] * inv, ct[ht][4 * a + 1] * inv) |
                          ((uint64_t)pk2bf(ct[ht][4 * a + 2] * inv, ct[ht][4 * a + 3] * inv) << 32);
            *(uint64_t*)&ctxb[base + hd] = pk;
        }
#undef STAGE
}

// ---------------- launch ----------------
extern "C" void kernel_launch(void* const* d_in, const int* in_sizes, int n_in,
                              void* d_out, int out_size, void* d_ws, size_t ws_size,
                              hipStream_t stream) {
    (void)in_sizes; (void)n_in; (void)out_size; (void)ws_size;
    const float* x  = (const float*)d_in[0];
    const float* Wq = (const float*)d_in[1];
    const float* bq = (const float*)d_in[2];
    const float* Wk = (const float*)d_in[3];
    const float* bk = (const float*)d_in[4];
    const float* Wv = (const float*)d_in[5];
    const float* bv = (const float*)d_in[6];
    const float* Wo = (const float*)d_in[7];
    const float* bo = (const float*)d_in[8];
    char* ws = (char*)d_ws;
    u16* xb   = (u16*)(ws);               // 4096*768 bf16      = 6291456 B
    u16* wqt  = (u16*)(ws + 6291456);     // 768*768 bf16 (W^T) = 1179648 B
    u16* wkt  = (u16*)(ws + 7471104);
    u16* wvt  = (u16*)(ws + 8650752);
    u16* wot  = (u16*)(ws + 9830400);
    u16* qwv  = (u16*)(ws + 11010048);    // [24][2048][64] bf16 (Q pre-scaled by C2)
    u16* kwv  = (u16*)(ws + 17301504);
    u16* vtw  = (u16*)(ws + 23592960);    // V^T [24][64][2048] bf16
    u16* ctx  = (u16*)(ws + 29884416);    // [4096][768] bf16
    float* out = (float*)d_out;

    k_cvt_bf16<<<1536, 256, 0, stream>>>(x, xb);
    k_transpose_w<<<dim3(24, 24, 4), dim3(32, 8), 0, stream>>>(Wq, Wk, Wv, Wo, wqt, wkt, wvt, wot);
    k_gemm128<0><<<dim3(18, 32), 256, 0, stream>>>(xb, wqt, wkt, wvt, bq, bk, bv,
                                                   qwv, kwv, vtw, nullptr);
    k_attn<<<384, 256, 0, stream>>>(qwv, kwv, vtw, ctx);
    k_gemm128<1><<<dim3(6, 32), 256, 0, stream>>>(ctx, wot, nullptr, nullptr, bo, nullptr, nullptr,
                                                  nullptr, nullptr, nullptr, out);
}

// Round 6
// 172.568 us; speedup vs baseline: 1.3135x; 1.1538x over previous
//
#include <hip/hip_runtime.h>
#include <stdint.h>

typedef unsigned short u16;
typedef __attribute__((ext_vector_type(8))) short s16x8;
typedef __attribute__((ext_vector_type(4))) float f32x4;
typedef __attribute__((ext_vector_type(16))) float f32x16;

#define MFMA_BF16(a, b, c) __builtin_amdgcn_mfma_f32_16x16x32_bf16((a), (b), (c), 0, 0, 0)
#define MFMA32(a, b, c) __builtin_amdgcn_mfma_f32_32x32x16_bf16((a), (b), (c), 0, 0, 0)

typedef const __attribute__((address_space(1))) uint32_t* gas1_t;
typedef __attribute__((address_space(3))) uint32_t* las3_t;
#define GLDS16(dst, src) __builtin_amdgcn_global_load_lds((gas1_t)(src), (las3_t)(dst), 16, 0, 0)

static __device__ __forceinline__ u16 f2bf(float f) {
    uint32_t u = __float_as_uint(f);
    u = (u + 0x7fffu + ((u >> 16) & 1u)) >> 16;
    return (u16)u;
}
static __device__ __forceinline__ uint32_t pk2bf(float a, float b) {
    return (uint32_t)f2bf(a) | ((uint32_t)f2bf(b) << 16);
}

// ---------------- f32 -> bf16 linear convert (x) ----------------
__global__ void k_cvt_bf16(const float* __restrict__ in, u16* __restrict__ out) {
    int i = (blockIdx.x * 256 + threadIdx.x) * 8;
    f32x4 a = *(const f32x4*)(in + i);
    f32x4 b = *(const f32x4*)(in + i + 4);
    s16x8 r;
    r[0] = (short)f2bf(a[0]); r[1] = (short)f2bf(a[1]);
    r[2] = (short)f2bf(a[2]); r[3] = (short)f2bf(a[3]);
    r[4] = (short)f2bf(b[0]); r[5] = (short)f2bf(b[1]);
    r[6] = (short)f2bf(b[2]); r[7] = (short)f2bf(b[3]);
    *(s16x8*)(out + i) = r;
}

// ---------------- W [k][n] f32 -> Wt [n][k] bf16 (768x768, 4 weights) ----------------
__global__ void k_transpose_w(const float* __restrict__ w0, const float* __restrict__ w1,
                              const float* __restrict__ w2, const float* __restrict__ w3,
                              u16* __restrict__ t0, u16* __restrict__ t1,
                              u16* __restrict__ t2, u16* __restrict__ t3) {
    __shared__ float tile[32][33];
    const float* W; u16* T;
    switch (blockIdx.z) {
        case 0:  W = w0; T = t0; break;
        case 1:  W = w1; T = t1; break;
        case 2:  W = w2; T = t2; break;
        default: W = w3; T = t3; break;
    }
    int n0 = blockIdx.x * 32, k0 = blockIdx.y * 32;
    int tx = threadIdx.x, ty = threadIdx.y;
#pragma unroll
    for (int i = 0; i < 4; ++i)
        tile[ty + 8 * i][tx] = W[(size_t)(k0 + ty + 8 * i) * 768 + n0 + tx];
    __syncthreads();
#pragma unroll
    for (int i = 0; i < 4; ++i)
        T[(size_t)(n0 + ty + 8 * i) * 768 + k0 + tx] = f2bf(tile[tx][ty + 8 * i]);
}

// ---------------- fused QKV GEMM: 128x64 tiles (n-tile == one head) ----------------
// grid (36, 32): bx/12 -> sel(0=Q,1=K,2=V), bx%12 -> head. Q scaled by C2.
// sel 0/1 scatter [bh][s][64] bf16; sel 2 scatters V^T [bh][64][s] bf16.
__global__ __launch_bounds__(256) void k_gemm_qkv(
        const u16* __restrict__ A,
        const u16* __restrict__ btq, const u16* __restrict__ btk, const u16* __restrict__ btv,
        const float* __restrict__ bq, const float* __restrict__ bk, const float* __restrict__ bv,
        u16* __restrict__ outq, u16* __restrict__ outk, u16* __restrict__ outv) {
    __shared__ u16 lA[128 * 64];
    __shared__ u16 lB[64 * 64];
    const int bx = blockIdx.x, sel = bx / 12, nb = bx - sel * 12;
    const u16* Bt; const float* bias;
    if (sel == 0)      { Bt = btq; bias = bq; }
    else if (sel == 1) { Bt = btk; bias = bk; }
    else               { Bt = btv; bias = bv; }
    const int t = threadIdx.x, lane = t & 63, w = t >> 6;
    const int wr = w >> 1, wc = w & 1;
    const int c = lane & 15, g = lane >> 4;
    const int m0 = blockIdx.y * 128, n0 = nb * 64;
    f32x4 acc[4][2] = {};
    // staging: linear LDS dest, pre-swizzled global source (granule ^ (row&7))
    const int lr = lane >> 3, lg = lane & 7;
    const int swz8 = 8 * (lg ^ lr);
    const u16* gA = A  + (size_t)(m0 + w * 8 + lr) * 768 + swz8;
    const u16* gB = Bt + (size_t)(n0 + w * 8 + lr) * 768 + swz8;
    for (int kb = 0; kb < 768; kb += 64) {
#pragma unroll
        for (int j = 0; j < 4; ++j)
            GLDS16(&lA[j * 2048 + w * 512], gA + (size_t)j * 32 * 768 + kb);
#pragma unroll
        for (int j = 0; j < 2; ++j)
            GLDS16(&lB[j * 2048 + w * 512], gB + (size_t)j * 32 * 768 + kb);
        __syncthreads();
#pragma unroll
        for (int kh = 0; kh < 2; ++kh) {
            s16x8 af[4], bfr[2];
            const int gg = kh * 4 + g;
#pragma unroll
            for (int i = 0; i < 4; ++i) {
                const int ra = wr * 64 + i * 16 + c;
                af[i] = *(const s16x8*)&lA[ra * 64 + 8 * (gg ^ (ra & 7))];
            }
#pragma unroll
            for (int j = 0; j < 2; ++j) {
                const int rb = wc * 32 + j * 16 + c;
                bfr[j] = *(const s16x8*)&lB[rb * 64 + 8 * (gg ^ (rb & 7))];
            }
#pragma unroll
            for (int i = 0; i < 4; ++i)
#pragma unroll
                for (int j = 0; j < 2; ++j)
                    acc[i][j] = MFMA_BF16(af[i], bfr[j], acc[i][j]);
        }
        __syncthreads();
    }
    const float C2 = 0.18033688011112042f;  // (1/8)*log2(e), folded into Q
    const int h = nb;
    if (sel < 2) {
        u16* outp = (sel == 0) ? outq : outk;
        const float osc = (sel == 0) ? C2 : 1.0f;
#pragma unroll
        for (int i = 0; i < 4; ++i)
#pragma unroll
            for (int j = 0; j < 2; ++j) {
                const int hd = wc * 32 + j * 16 + c;
                const float bvv = bias[n0 + hd];
#pragma unroll
                for (int rr = 0; rr < 4; ++rr) {
                    const int m = m0 + wr * 64 + i * 16 + g * 4 + rr;
                    const int b = m >> 11, s = m & 2047;
                    outp[(((size_t)(b * 12 + h) * 2048 + s) << 6) + hd] =
                        f2bf((acc[i][j][rr] + bvv) * osc);
                }
            }
    } else {        // V^T: [bh][hd][s], 4 consecutive s packed
#pragma unroll
        for (int i = 0; i < 4; ++i)
#pragma unroll
            for (int j = 0; j < 2; ++j) {
                const int hd = wc * 32 + j * 16 + c;
                const float bvv = bias[n0 + hd];
                const int m = m0 + wr * 64 + i * 16 + g * 4;
                const int b = m >> 11, s = m & 2047;
                uint64_t pk = (uint64_t)pk2bf(acc[i][j][0] + bvv, acc[i][j][1] + bvv) |
                              ((uint64_t)pk2bf(acc[i][j][2] + bvv, acc[i][j][3] + bvv) << 32);
                *(uint64_t*)&outv[((size_t)(b * 12 + h) * 64 + hd) * 2048 + s] = pk;
            }
    }
}

// ---------------- out-projection GEMM: 64x64 (round-3 verbatim) ----------------
__global__ __launch_bounds__(256) void k_gemm_out(const u16* __restrict__ A,
                                                  const u16* __restrict__ Bt,
                                                  const float* __restrict__ bias,
                                                  float* __restrict__ out) {
    __shared__ u16 lA[64 * 64];
    __shared__ u16 lB[64 * 64];
    const int t = threadIdx.x;
    const int lane = t & 63, w = t >> 6;
    const int wr = w >> 1, wc = w & 1;
    const int c = lane & 15, g = lane >> 4;
    const int m0 = blockIdx.y * 64, n0 = blockIdx.x * 64;
    f32x4 acc[2][2] = {};
    const int lr = lane >> 3, lq = lane & 7;
    const int sq = (lq ^ lr) * 8;
    const u16* gA0 = A  + (size_t)(m0 + w * 16 + lr) * 768 + sq;
    const u16* gA1 = gA0 + 8 * 768;
    const u16* gB0 = Bt + (size_t)(n0 + w * 16 + lr) * 768 + sq;
    const u16* gB1 = gB0 + 8 * 768;
    u16* dA0 = &lA[w * 1024];
    u16* dA1 = &lA[w * 1024 + 512];
    u16* dB0 = &lB[w * 1024];
    u16* dB1 = &lB[w * 1024 + 512];
    for (int kb = 0; kb < 768; kb += 64) {
        GLDS16(dA0, gA0 + kb); GLDS16(dA1, gA1 + kb);
        GLDS16(dB0, gB0 + kb); GLDS16(dB1, gB1 + kb);
        __syncthreads();
#pragma unroll
        for (int st = 0; st < 2; ++st) {
            s16x8 af[2], bf[2];
            const int col = st * 32 + g * 8;
#pragma unroll
            for (int i = 0; i < 2; ++i) {
                int ra = wr * 32 + i * 16 + c;
                af[i] = *(const s16x8*)&lA[ra * 64 + (col ^ ((ra & 7) << 3))];
                int rb = wc * 32 + i * 16 + c;
                bf[i] = *(const s16x8*)&lB[rb * 64 + (col ^ ((rb & 7) << 3))];
            }
#pragma unroll
            for (int i = 0; i < 2; ++i)
#pragma unroll
                for (int j = 0; j < 2; ++j)
                    acc[i][j] = MFMA_BF16(af[i], bf[j], acc[i][j]);
        }
        __syncthreads();
    }
#pragma unroll
    for (int i = 0; i < 2; ++i)
#pragma unroll
        for (int j = 0; j < 2; ++j) {
            const int n = n0 + wc * 32 + j * 16 + c;
            const float bvv = bias[n];
#pragma unroll
            for (int rr = 0; rr < 4; ++rr) {
                const int m = m0 + wr * 32 + i * 16 + g * 4 + rr;
                out[(size_t)m * 768 + n] = acc[i][j][rr] + bvv;
            }
        }
}

// ---------------- causal flash attention: 2 waves x 32 q-rows, 32x32 MFMA ----------------
// grid = 24*32 = 768 blocks x 128 thr, descending-work order.
// K/V double-buffered via global_load_lds; counted vmcnt(8); s_setprio around MFMA.
__global__ __launch_bounds__(128) void k_attn(const u16* __restrict__ qw,
                                              const u16* __restrict__ kw,
                                              const u16* __restrict__ vt,
                                              u16* __restrict__ ctxb) {
    __shared__ u16 lK[2][64 * 64];   // [key][hd], XOR-swizzled (granule ^ row&7)
    __shared__ u16 lV[2][64 * 64];   // V^T [hd][key], same swizzle
    const int bid = blockIdx.x;
    const int qt = 31 - bid / 24;    // heavy tiles first
    const int bh = bid % 24;
    const int t = threadIdx.x, lane = t & 63, w = t >> 6;   // w in {0,1}
    const int l31 = lane & 31, hi = lane >> 5;
    const int q0w = qt * 64 + w * 32;
    const u16* qp = qw + (size_t)bh * 2048 * 64;
    const u16* kp = kw + (size_t)bh * 2048 * 64;
    const u16* vp = vt + (size_t)bh * 64 * 2048;
    // Q B-frags (pre-scaled by C2): col=q=l31
    s16x8 qf[4];
#pragma unroll
    for (int dk = 0; dk < 4; ++dk)
        qf[dk] = *(const s16x8*)&qp[(size_t)(q0w + l31) * 64 + dk * 16 + hi * 8];
    asm volatile("s_waitcnt vmcnt(0)" ::: "memory");
    // staging: 8 GLDS16 per wave per chunk (4 K sites + 4 V sites, 16 rows each)
    const int lr = lane >> 3, lg = lane & 7;
    const int swz8 = 8 * (lg ^ lr);
    const u16* kpb = kp + (size_t)(w * 8 + lr) * 64 + swz8;
    const u16* vpb = vp + (size_t)(w * 8 + lr) * 2048 + swz8;
    const int NC = qt + 1;
    const int lastq = q0w + 31;
    f32x16 ct[2] = {};               // ctx^T: col=q, rows=hd
    float m2 = -1e30f, ssum = 0.0f;
#define STAGE(bf, ch)                                                          \
    {                                                                          \
        const u16* ks_ = kpb + (size_t)(ch) * 4096;                            \
        GLDS16(&lK[bf][(w * 8) * 64], ks_);                                    \
        GLDS16(&lK[bf][(16 + w * 8) * 64], ks_ + 16 * 64);                     \
        GLDS16(&lK[bf][(32 + w * 8) * 64], ks_ + 32 * 64);                     \
        GLDS16(&lK[bf][(48 + w * 8) * 64], ks_ + 48 * 64);                     \
        const u16* vs_ = vpb + (size_t)(ch) * 64;                              \
        GLDS16(&lV[bf][(w * 8) * 64], vs_);                                    \
        GLDS16(&lV[bf][(16 + w * 8) * 64], vs_ + 16 * 2048);                   \
        GLDS16(&lV[bf][(32 + w * 8) * 64], vs_ + 32 * 2048);                   \
        GLDS16(&lV[bf][(48 + w * 8) * 64], vs_ + 48 * 2048);                   \
    }
    STAGE(0, 0);
    for (int ch = 0; ch < NC; ++ch) {
        const int bf = ch & 1, Kc = ch * 64;
        if (ch + 1 < NC) {
            STAGE(bf ^ 1, ch + 1);
            asm volatile("s_waitcnt vmcnt(8)" ::: "memory");   // cur buffer landed
        } else {
            asm volatile("s_waitcnt vmcnt(0)" ::: "memory");
        }
        __builtin_amdgcn_sched_barrier(0);
        __builtin_amdgcn_s_barrier();
        {
            // ---- QK^T: S^T[key][q], two 32-key tiles ----
            f32x16 st[2] = {};
            __builtin_amdgcn_s_setprio(1);
#pragma unroll
            for (int dk = 0; dk < 4; ++dk) {
                const int gr = dk * 2 + hi;
                const int r0 = l31, r1 = 32 + l31;
                s16x8 kf0 = *(const s16x8*)&lK[bf][r0 * 64 + 8 * (gr ^ (r0 & 7))];
                s16x8 kf1 = *(const s16x8*)&lK[bf][r1 * 64 + 8 * (gr ^ (r1 & 7))];
                st[0] = MFMA32(kf0, qf[dk], st[0]);
                st[1] = MFMA32(kf1, qf[dk], st[1]);
            }
            __builtin_amdgcn_s_setprio(0);
            // ---- mask (diagonal chunk only) ----
            const int qg = q0w + l31;
            float tv[32];
            if (Kc + 63 <= q0w) {
#pragma unroll
                for (int j = 0; j < 16; ++j) { tv[j] = st[0][j]; tv[16 + j] = st[1][j]; }
            } else {
                const int kb = Kc + 4 * hi;
#pragma unroll
                for (int j = 0; j < 16; ++j) {
                    const int kloc = (j & 3) + 8 * (j >> 2);
                    tv[j]      = (kb + kloc      <= qg) ? st[0][j] : -1e30f;
                    tv[16 + j] = (kb + kloc + 32 <= qg) ? st[1][j] : -1e30f;
                }
            }
            // ---- defer-max online softmax ----
            float mt = tv[0];
#pragma unroll
            for (int j = 1; j < 32; ++j) mt = fmaxf(mt, tv[j]);
            if (!__all(mt <= m2 + 8.0f)) {
                float mq = fmaxf(mt, __shfl_xor(mt, 32));
                const float mnew = fmaxf(m2, mq);
                const float fac = __builtin_amdgcn_exp2f(m2 - mnew);
                ssum *= fac;
#pragma unroll
                for (int j = 0; j < 16; ++j) { ct[0][j] *= fac; ct[1][j] *= fac; }
                m2 = mnew;
            }
            float p[32];
#pragma unroll
            for (int j = 0; j < 32; ++j) { p[j] = __builtin_amdgcn_exp2f(tv[j] - m2); ssum += p[j]; }
            // ---- P -> bf16 B-frags in-register; PV ----
#pragma unroll
            for (int kt = 0; kt < 2; ++kt) {
                uint32_t pcv[8];
#pragma unroll
                for (int x = 0; x < 8; ++x) {
                    const int j = kt * 16 + 4 * (x >> 1) + 2 * (x & 1);
                    asm volatile("v_cvt_pk_bf16_f32 %0, %1, %2"
                                 : "=v"(pcv[x]) : "v"(p[j]), "v"(p[j + 1]));
                }
#pragma unroll
                for (int kl = 0; kl < 2; ++kl) {
                    const uint32_t s0 = hi ? pcv[4 * kl]     : pcv[4 * kl + 2];
                    const uint32_t s1 = hi ? pcv[4 * kl + 1] : pcv[4 * kl + 3];
                    const uint32_t r0 = __shfl_xor(s0, 32);
                    const uint32_t r1 = __shfl_xor(s1, 32);
                    union { uint32_t u[4]; s16x8 v; } pf;
                    pf.u[0] = hi ? r0 : pcv[4 * kl];
                    pf.u[1] = hi ? r1 : pcv[4 * kl + 1];
                    pf.u[2] = hi ? pcv[4 * kl + 2] : r0;
                    pf.u[3] = hi ? pcv[4 * kl + 3] : r1;
                    const int gr = (kt * 2 + kl) * 2 + hi;
                    const int rv0 = l31, rv1 = 32 + l31;
                    s16x8 vf0 = *(const s16x8*)&lV[bf][rv0 * 64 + 8 * (gr ^ (rv0 & 7))];
                    s16x8 vf1 = *(const s16x8*)&lV[bf][rv1 * 64 + 8 * (gr ^ (rv1 & 7))];
                    __builtin_amdgcn_s_setprio(1);
                    ct[0] = MFMA32(vf0, pf.v, ct[0]);
                    ct[1] = MFMA32(vf1, pf.v, ct[1]);
                    __builtin_amdgcn_s_setprio(0);
                }
            }
        }
        __builtin_amdgcn_s_barrier();
    }
    // ---- finalize ----
    ssum += __shfl_xor(ssum, 32);
    const float inv = 1.0f / ssum;
    const int b = bh / 12, h = bh - b * 12;
    const size_t base = (size_t)(b * 2048 + q0w + l31) * 768 + h * 64;
#pragma unroll
    for (int ht = 0; ht < 2; ++ht)
#pragma unroll
        for (int a = 0; a < 4; ++a) {
            const int hd = ht * 32 + 8 * a + 4 * hi;
            uint64_t pk = (uint64_t)pk2bf(ct[ht][4 * a] * inv, ct[ht][4 * a + 1] * inv) |
                          ((uint64_t)pk2bf(ct[ht][4 * a + 2] * inv, ct[ht][4 * a + 3] * inv) << 32);
            *(uint64_t*)&ctxb[base + hd] = pk;
        }
#undef STAGE
}

// ---------------- launch ----------------
extern "C" void kernel_launch(void* const* d_in, const int* in_sizes, int n_in,
                              void* d_out, int out_size, void* d_ws, size_t ws_size,
                              hipStream_t stream) {
    (void)in_sizes; (void)n_in; (void)out_size; (void)ws_size;
    const float* x  = (const float*)d_in[0];
    const float* Wq = (const float*)d_in[1];
    const float* bq = (const float*)d_in[2];
    const float* Wk = (const float*)d_in[3];
    const float* bk = (const float*)d_in[4];
    const float* Wv = (const float*)d_in[5];
    const float* bv = (const float*)d_in[6];
    const float* Wo = (const float*)d_in[7];
    const float* bo = (const float*)d_in[8];
    char* ws = (char*)d_ws;
    u16* xb   = (u16*)(ws);               // 4096*768 bf16      = 6291456 B
    u16* wqt  = (u16*)(ws + 6291456);     // 768*768 bf16 (W^T) = 1179648 B
    u16* wkt  = (u16*)(ws + 7471104);
    u16* wvt  = (u16*)(ws + 8650752);
    u16* wot  = (u16*)(ws + 9830400);
    u16* qwv  = (u16*)(ws + 11010048);    // [24][2048][64] bf16 (Q pre-scaled by C2)
    u16* kwv  = (u16*)(ws + 17301504);
    u16* vtw  = (u16*)(ws + 23592960);    // V^T [24][64][2048] bf16
    u16* ctx  = (u16*)(ws + 29884416);    // [4096][768] bf16
    float* out = (float*)d_out;

    k_cvt_bf16<<<1536, 256, 0, stream>>>(x, xb);
    k_transpose_w<<<dim3(24, 24, 4), dim3(32, 8), 0, stream>>>(Wq, Wk, Wv, Wo, wqt, wkt, wvt, wot);
    k_gemm_qkv<<<dim3(36, 32), 256, 0, stream>>>(xb, wqt, wkt, wvt, bq, bk, bv, qwv, kwv, vtw);
    k_attn<<<768, 128, 0, stream>>>(qwv, kwv, vtw, ctx);
    k_gemm_out<<<dim3(12, 64), 256, 0, stream>>>(ctx, wot, bo, out);
}

// Round 7
// 162.115 us; speedup vs baseline: 1.3982x; 1.0645x over previous
//
#include <hip/hip_runtime.h>
#include <stdint.h>

typedef unsigned short u16;
typedef __attribute__((ext_vector_type(8))) short s16x8;
typedef __attribute__((ext_vector_type(4))) float f32x4;
typedef __attribute__((ext_vector_type(16))) float f32x16;

#define MFMA_BF16(a, b, c) __builtin_amdgcn_mfma_f32_16x16x32_bf16((a), (b), (c), 0, 0, 0)
#define MFMA32(a, b, c) __builtin_amdgcn_mfma_f32_32x32x16_bf16((a), (b), (c), 0, 0, 0)

typedef const __attribute__((address_space(1))) uint32_t* gas1_t;
typedef __attribute__((address_space(3))) uint32_t* las3_t;
#define GLDS16(dst, src) __builtin_amdgcn_global_load_lds((gas1_t)(src), (las3_t)(dst), 16, 0, 0)

static __device__ __forceinline__ u16 f2bf(float f) {
    uint32_t u = __float_as_uint(f);
    u = (u + 0x7fffu + ((u >> 16) & 1u)) >> 16;
    return (u16)u;
}
static __device__ __forceinline__ uint32_t pk2bf(float a, float b) {
    return (uint32_t)f2bf(a) | ((uint32_t)f2bf(b) << 16);
}
static __device__ __forceinline__ float bf2f(u16 h) {
    return __uint_as_float(((uint32_t)h) << 16);
}

// ---------------- f32 -> bf16 linear convert (x) ----------------
__global__ void k_cvt_bf16(const float* __restrict__ in, u16* __restrict__ out) {
    int i = (blockIdx.x * 256 + threadIdx.x) * 8;
    f32x4 a = *(const f32x4*)(in + i);
    f32x4 b = *(const f32x4*)(in + i + 4);
    s16x8 r;
    r[0] = (short)f2bf(a[0]); r[1] = (short)f2bf(a[1]);
    r[2] = (short)f2bf(a[2]); r[3] = (short)f2bf(a[3]);
    r[4] = (short)f2bf(b[0]); r[5] = (short)f2bf(b[1]);
    r[6] = (short)f2bf(b[2]); r[7] = (short)f2bf(b[3]);
    *(s16x8*)(out + i) = r;
}

// ---------------- W [k][n] f32 -> Wt [n][k] bf16 (768x768, 4 weights) ----------------
__global__ void k_transpose_w(const float* __restrict__ w0, const float* __restrict__ w1,
                              const float* __restrict__ w2, const float* __restrict__ w3,
                              u16* __restrict__ t0, u16* __restrict__ t1,
                              u16* __restrict__ t2, u16* __restrict__ t3) {
    __shared__ float tile[32][33];
    const float* W; u16* T;
    switch (blockIdx.z) {
        case 0:  W = w0; T = t0; break;
        case 1:  W = w1; T = t1; break;
        case 2:  W = w2; T = t2; break;
        default: W = w3; T = t3; break;
    }
    int n0 = blockIdx.x * 32, k0 = blockIdx.y * 32;
    int tx = threadIdx.x, ty = threadIdx.y;
#pragma unroll
    for (int i = 0; i < 4; ++i)
        tile[ty + 8 * i][tx] = W[(size_t)(k0 + ty + 8 * i) * 768 + n0 + tx];
    __syncthreads();
#pragma unroll
    for (int i = 0; i < 4; ++i)
        T[(size_t)(n0 + ty + 8 * i) * 768 + k0 + tx] = f2bf(tile[tx][ty + 8 * i]);
}

// ---------------- fused QKV GEMM: 128x64 tiles (n-tile == one head) ----------------
__global__ __launch_bounds__(256) void k_gemm_qkv(
        const u16* __restrict__ A,
        const u16* __restrict__ btq, const u16* __restrict__ btk, const u16* __restrict__ btv,
        const float* __restrict__ bq, const float* __restrict__ bk, const float* __restrict__ bv,
        u16* __restrict__ outq, u16* __restrict__ outk, u16* __restrict__ outv) {
    __shared__ u16 lA[128 * 64];
    __shared__ u16 lB[64 * 64];
    const int bx = blockIdx.x, sel = bx / 12, nb = bx - sel * 12;
    const u16* Bt; const float* bias;
    if (sel == 0)      { Bt = btq; bias = bq; }
    else if (sel == 1) { Bt = btk; bias = bk; }
    else               { Bt = btv; bias = bv; }
    const int t = threadIdx.x, lane = t & 63, w = t >> 6;
    const int wr = w >> 1, wc = w & 1;
    const int c = lane & 15, g = lane >> 4;
    const int m0 = blockIdx.y * 128, n0 = nb * 64;
    f32x4 acc[4][2] = {};
    const int lr = lane >> 3, lg = lane & 7;
    const int swz8 = 8 * (lg ^ lr);
    const u16* gA = A  + (size_t)(m0 + w * 8 + lr) * 768 + swz8;
    const u16* gB = Bt + (size_t)(n0 + w * 8 + lr) * 768 + swz8;
    for (int kb = 0; kb < 768; kb += 64) {
#pragma unroll
        for (int j = 0; j < 4; ++j)
            GLDS16(&lA[j * 2048 + w * 512], gA + (size_t)j * 32 * 768 + kb);
#pragma unroll
        for (int j = 0; j < 2; ++j)
            GLDS16(&lB[j * 2048 + w * 512], gB + (size_t)j * 32 * 768 + kb);
        __syncthreads();
#pragma unroll
        for (int kh = 0; kh < 2; ++kh) {
            s16x8 af[4], bfr[2];
            const int gg = kh * 4 + g;
#pragma unroll
            for (int i = 0; i < 4; ++i) {
                const int ra = wr * 64 + i * 16 + c;
                af[i] = *(const s16x8*)&lA[ra * 64 + 8 * (gg ^ (ra & 7))];
            }
#pragma unroll
            for (int j = 0; j < 2; ++j) {
                const int rb = wc * 32 + j * 16 + c;
                bfr[j] = *(const s16x8*)&lB[rb * 64 + 8 * (gg ^ (rb & 7))];
            }
#pragma unroll
            for (int i = 0; i < 4; ++i)
#pragma unroll
                for (int j = 0; j < 2; ++j)
                    acc[i][j] = MFMA_BF16(af[i], bfr[j], acc[i][j]);
        }
        __syncthreads();
    }
    const float C2 = 0.18033688011112042f;  // (1/8)*log2(e), folded into Q
    const int h = nb;
    if (sel < 2) {
        u16* outp = (sel == 0) ? outq : outk;
        const float osc = (sel == 0) ? C2 : 1.0f;
#pragma unroll
        for (int i = 0; i < 4; ++i)
#pragma unroll
            for (int j = 0; j < 2; ++j) {
                const int hd = wc * 32 + j * 16 + c;
                const float bvv = bias[n0 + hd];
#pragma unroll
                for (int rr = 0; rr < 4; ++rr) {
                    const int m = m0 + wr * 64 + i * 16 + g * 4 + rr;
                    const int b = m >> 11, s = m & 2047;
                    outp[(((size_t)(b * 12 + h) * 2048 + s) << 6) + hd] =
                        f2bf((acc[i][j][rr] + bvv) * osc);
                }
            }
    } else {
#pragma unroll
        for (int i = 0; i < 4; ++i)
#pragma unroll
            for (int j = 0; j < 2; ++j) {
                const int hd = wc * 32 + j * 16 + c;
                const float bvv = bias[n0 + hd];
                const int m = m0 + wr * 64 + i * 16 + g * 4;
                const int b = m >> 11, s = m & 2047;
                uint64_t pk = (uint64_t)pk2bf(acc[i][j][0] + bvv, acc[i][j][1] + bvv) |
                              ((uint64_t)pk2bf(acc[i][j][2] + bvv, acc[i][j][3] + bvv) << 32);
                *(uint64_t*)&outv[((size_t)(b * 12 + h) * 64 + hd) * 2048 + s] = pk;
            }
    }
}

// ---------------- out-projection GEMM: 64x64 ----------------
__global__ __launch_bounds__(256) void k_gemm_out(const u16* __restrict__ A,
                                                  const u16* __restrict__ Bt,
                                                  const float* __restrict__ bias,
                                                  float* __restrict__ out) {
    __shared__ u16 lA[64 * 64];
    __shared__ u16 lB[64 * 64];
    const int t = threadIdx.x;
    const int lane = t & 63, w = t >> 6;
    const int wr = w >> 1, wc = w & 1;
    const int c = lane & 15, g = lane >> 4;
    const int m0 = blockIdx.y * 64, n0 = blockIdx.x * 64;
    f32x4 acc[2][2] = {};
    const int lr = lane >> 3, lq = lane & 7;
    const int sq = (lq ^ lr) * 8;
    const u16* gA0 = A  + (size_t)(m0 + w * 16 + lr) * 768 + sq;
    const u16* gA1 = gA0 + 8 * 768;
    const u16* gB0 = Bt + (size_t)(n0 + w * 16 + lr) * 768 + sq;
    const u16* gB1 = gB0 + 8 * 768;
    u16* dA0 = &lA[w * 1024];
    u16* dA1 = &lA[w * 1024 + 512];
    u16* dB0 = &lB[w * 1024];
    u16* dB1 = &lB[w * 1024 + 512];
    for (int kb = 0; kb < 768; kb += 64) {
        GLDS16(dA0, gA0 + kb); GLDS16(dA1, gA1 + kb);
        GLDS16(dB0, gB0 + kb); GLDS16(dB1, gB1 + kb);
        __syncthreads();
#pragma unroll
        for (int st = 0; st < 2; ++st) {
            s16x8 af[2], bf[2];
            const int col = st * 32 + g * 8;
#pragma unroll
            for (int i = 0; i < 2; ++i) {
                int ra = wr * 32 + i * 16 + c;
                af[i] = *(const s16x8*)&lA[ra * 64 + (col ^ ((ra & 7) << 3))];
                int rb = wc * 32 + i * 16 + c;
                bf[i] = *(const s16x8*)&lB[rb * 64 + (col ^ ((rb & 7) << 3))];
            }
#pragma unroll
            for (int i = 0; i < 2; ++i)
#pragma unroll
                for (int j = 0; j < 2; ++j)
                    acc[i][j] = MFMA_BF16(af[i], bf[j], acc[i][j]);
        }
        __syncthreads();
    }
#pragma unroll
    for (int i = 0; i < 2; ++i)
#pragma unroll
        for (int j = 0; j < 2; ++j) {
            const int n = n0 + wc * 32 + j * 16 + c;
            const float bvv = bias[n];
#pragma unroll
            for (int rr = 0; rr < 4; ++rr) {
                const int m = m0 + wr * 32 + i * 16 + g * 4 + rr;
                out[(size_t)m * 768 + n] = acc[i][j][rr] + bvv;
            }
        }
}

// ---------------- causal flash attention: split-K across blocks ----------------
// Block = 2 waves x 32 q-rows (64-row tile), one 512-key segment (<=8 chunks).
// Split tiles (nseg>1) emit unnormalized bf16 partials + (m, ssum); combine kernel merges.
// grid = 80 slots * 24 bh = 1920 blocks x 128 thr, heavy slots first.
__global__ __launch_bounds__(128) void k_attn(const u16* __restrict__ qw,
                                              const u16* __restrict__ kw,
                                              const u16* __restrict__ vt,
                                              u16* __restrict__ ctxb,
                                              u16* __restrict__ pctx,
                                              float* __restrict__ pm,
                                              float* __restrict__ ps) {
    __shared__ u16 lK[2][64 * 64];   // [key][hd], XOR-swizzled (granule ^ row&7)
    __shared__ u16 lV[2][64 * 64];   // V^T [hd][key], same swizzle
    const int bid = blockIdx.x;
    const int slot = bid / 24, bh = bid - slot * 24;
    int qt64, seg;
    if (slot < 32)      { qt64 = 31 - (slot >> 2); seg = slot & 3; }
    else if (slot < 56) { const int u = slot - 32; const int d3 = u / 3; qt64 = 23 - d3; seg = u - d3 * 3; }
    else if (slot < 72) { const int u = slot - 56; qt64 = 15 - (u >> 1); seg = u & 1; }
    else                { qt64 = 79 - slot; seg = 0; }
    const int nseg = (qt64 >> 3) + 1;
    const int ch0 = seg * 8;
    const int nchunks = qt64 + 1 - ch0;
    const int nch = nchunks < 8 ? nchunks : 8;
    const int t = threadIdx.x, lane = t & 63, w = t >> 6;   // w in {0,1}
    const int l31 = lane & 31, hi = lane >> 5;
    const int q0w = qt64 * 64 + w * 32;
    const u16* qp = qw + (size_t)bh * 2048 * 64;
    const u16* kp = kw + (size_t)bh * 2048 * 64;
    const u16* vp = vt + (size_t)bh * 64 * 2048;
    s16x8 qf[4];
#pragma unroll
    for (int dk = 0; dk < 4; ++dk)
        qf[dk] = *(const s16x8*)&qp[(size_t)(q0w + l31) * 64 + dk * 16 + hi * 8];
    asm volatile("s_waitcnt vmcnt(0)" ::: "memory");
    const int lr = lane >> 3, lg = lane & 7;
    const int swz8 = 8 * (lg ^ lr);
    const u16* kpb = kp + (size_t)(w * 8 + lr) * 64 + swz8;
    const u16* vpb = vp + (size_t)(w * 8 + lr) * 2048 + swz8;
    const int lastq = q0w + 31;
    f32x16 ct[2] = {};               // ctx^T: col=q, rows=hd
    float m2 = -1e30f, ssum = 0.0f;
#define STAGE(bf, ch)                                                          \
    {                                                                          \
        const u16* ks_ = kpb + (size_t)(ch) * 4096;                            \
        GLDS16(&lK[bf][(w * 8) * 64], ks_);                                    \
        GLDS16(&lK[bf][(16 + w * 8) * 64], ks_ + 16 * 64);                     \
        GLDS16(&lK[bf][(32 + w * 8) * 64], ks_ + 32 * 64);                     \
        GLDS16(&lK[bf][(48 + w * 8) * 64], ks_ + 48 * 64);                     \
        const u16* vs_ = vpb + (size_t)(ch) * 64;                              \
        GLDS16(&lV[bf][(w * 8) * 64], vs_);                                    \
        GLDS16(&lV[bf][(16 + w * 8) * 64], vs_ + 16 * 2048);                   \
        GLDS16(&lV[bf][(32 + w * 8) * 64], vs_ + 32 * 2048);                   \
        GLDS16(&lV[bf][(48 + w * 8) * 64], vs_ + 48 * 2048);                   \
    }
    STAGE(0, ch0);
    for (int ci = 0; ci < nch; ++ci) {
        const int bf = ci & 1, Kc = (ch0 + ci) * 64;
        if (ci + 1 < nch) {
            STAGE(bf ^ 1, ch0 + ci + 1);
            asm volatile("s_waitcnt vmcnt(8)" ::: "memory");
        } else {
            asm volatile("s_waitcnt vmcnt(0)" ::: "memory");
        }
        __builtin_amdgcn_sched_barrier(0);
        __builtin_amdgcn_s_barrier();
        if (Kc <= lastq) {           // wave-uniform causal skip
            f32x16 st[2] = {};
            __builtin_amdgcn_s_setprio(1);
#pragma unroll
            for (int dk = 0; dk < 4; ++dk) {
                const int gr = dk * 2 + hi;
                const int r0 = l31, r1 = 32 + l31;
                s16x8 kf0 = *(const s16x8*)&lK[bf][r0 * 64 + 8 * (gr ^ (r0 & 7))];
                s16x8 kf1 = *(const s16x8*)&lK[bf][r1 * 64 + 8 * (gr ^ (r1 & 7))];
                st[0] = MFMA32(kf0, qf[dk], st[0]);
                st[1] = MFMA32(kf1, qf[dk], st[1]);
            }
            __builtin_amdgcn_s_setprio(0);
            const int qg = q0w + l31;
            float tv[32];
            if (Kc + 63 <= q0w) {
#pragma unroll
                for (int j = 0; j < 16; ++j) { tv[j] = st[0][j]; tv[16 + j] = st[1][j]; }
            } else {
                const int kb = Kc + 4 * hi;
#pragma unroll
                for (int j = 0; j < 16; ++j) {
                    const int kloc = (j & 3) + 8 * (j >> 2);
                    tv[j]      = (kb + kloc      <= qg) ? st[0][j] : -1e30f;
                    tv[16 + j] = (kb + kloc + 32 <= qg) ? st[1][j] : -1e30f;
                }
            }
            // ---- tree max (depth 5 instead of serial 31) ----
            float x16[16], x8[8], x4[4];
#pragma unroll
            for (int j = 0; j < 16; ++j) x16[j] = fmaxf(tv[j], tv[j + 16]);
#pragma unroll
            for (int j = 0; j < 8; ++j) x8[j] = fmaxf(x16[j], x16[j + 8]);
#pragma unroll
            for (int j = 0; j < 4; ++j) x4[j] = fmaxf(x8[j], x8[j + 4]);
            const float mt = fmaxf(fmaxf(x4[0], x4[1]), fmaxf(x4[2], x4[3]));
            if (!__all(mt <= m2 + 8.0f)) {
                float mq = fmaxf(mt, __shfl_xor(mt, 32));
                const float mnew = fmaxf(m2, mq);
                const float fac = __builtin_amdgcn_exp2f(m2 - mnew);
                ssum *= fac;
#pragma unroll
                for (int j = 0; j < 16; ++j) { ct[0][j] *= fac; ct[1][j] *= fac; }
                m2 = mnew;
            }
            float p[32];
#pragma unroll
            for (int j = 0; j < 32; ++j) p[j] = __builtin_amdgcn_exp2f(tv[j] - m2);
            // ---- tree sum ----
            float y16[16], y8[8], y4[4];
#pragma unroll
            for (int j = 0; j < 16; ++j) y16[j] = p[j] + p[j + 16];
#pragma unroll
            for (int j = 0; j < 8; ++j) y8[j] = y16[j] + y16[j + 8];
#pragma unroll
            for (int j = 0; j < 4; ++j) y4[j] = y8[j] + y8[j + 4];
            ssum += (y4[0] + y4[1]) + (y4[2] + y4[3]);
            // ---- P -> bf16 B-frags via cvt_pk + permlane32_swap; PV ----
#pragma unroll
            for (int kt = 0; kt < 2; ++kt) {
                uint32_t pcv[8];
#pragma unroll
                for (int x = 0; x < 8; ++x) {
                    const int j = kt * 16 + 4 * (x >> 1) + 2 * (x & 1);
                    asm volatile("v_cvt_pk_bf16_f32 %0, %1, %2"
                                 : "=v"(pcv[x]) : "v"(p[j]), "v"(p[j + 1]));
                }
#pragma unroll
                for (int kl = 0; kl < 2; ++kl) {
                    uint32_t a0 = pcv[4 * kl],     b0 = pcv[4 * kl + 2];
                    uint32_t a1 = pcv[4 * kl + 1], b1 = pcv[4 * kl + 3];
                    asm volatile("v_permlane32_swap_b32 %0, %1" : "+v"(a0), "+v"(b0));
                    asm volatile("v_permlane32_swap_b32 %0, %1" : "+v"(a1), "+v"(b1));
                    union { uint32_t u[4]; s16x8 v; } pf;
                    pf.u[0] = a0; pf.u[1] = a1; pf.u[2] = b0; pf.u[3] = b1;
                    const int gr = (kt * 2 + kl) * 2 + hi;
                    const int rv0 = l31, rv1 = 32 + l31;
                    s16x8 vf0 = *(const s16x8*)&lV[bf][rv0 * 64 + 8 * (gr ^ (rv0 & 7))];
                    s16x8 vf1 = *(const s16x8*)&lV[bf][rv1 * 64 + 8 * (gr ^ (rv1 & 7))];
                    __builtin_amdgcn_s_setprio(1);
                    ct[0] = MFMA32(vf0, pf.v, ct[0]);
                    ct[1] = MFMA32(vf1, pf.v, ct[1]);
                    __builtin_amdgcn_s_setprio(0);
                }
            }
        }
        __builtin_amdgcn_s_barrier();
    }
    if (nseg == 1) {
        // direct write (tile fully computed by this block)
        ssum += __shfl_xor(ssum, 32);
        const float inv = 1.0f / ssum;
        const int b = bh / 12, h = bh - b * 12;
        const size_t base = (size_t)(b * 2048 + q0w + l31) * 768 + h * 64;
#pragma unroll
        for (int ht = 0; ht < 2; ++ht)
#pragma unroll
            for (int a = 0; a < 4; ++a) {
                const int hd = ht * 32 + 8 * a + 4 * hi;
                uint64_t pk = (uint64_t)pk2bf(ct[ht][4 * a] * inv, ct[ht][4 * a + 1] * inv) |
                              ((uint64_t)pk2bf(ct[ht][4 * a + 2] * inv, ct[ht][4 * a + 3] * inv) << 32);
                *(uint64_t*)&ctxb[base + hd] = pk;
            }
    } else {
        // partial write: unnormalized bf16 ctx + per-row (m, ssum)
        const float srow = ssum + __shfl_xor(ssum, 32);
        const int ti = (bh * 32 + qt64) * 4 + seg;
        const int row = w * 32 + l31;
        u16* pp = &pctx[(size_t)ti * 4096 + row * 64];
#pragma unroll
        for (int ht = 0; ht < 2; ++ht)
#pragma unroll
            for (int a = 0; a < 4; ++a) {
                const int hd = ht * 32 + 8 * a + 4 * hi;
                uint64_t pk = (uint64_t)pk2bf(ct[ht][4 * a], ct[ht][4 * a + 1]) |
                              ((uint64_t)pk2bf(ct[ht][4 * a + 2], ct[ht][4 * a + 3]) << 32);
                *(uint64_t*)&pp[hd] = pk;
            }
        if (hi == 0) {
            pm[ti * 64 + row] = m2;
            ps[ti * 64 + row] = srow;
        }
    }
#undef STAGE
}

// ---------------- split-K combine: merge <=4 segments per 64-row tile ----------------
// grid (24 bh, 24 qt-tiles [qt64=8..31]) x 256 thr; thread = 1 row x 16 hd.
__global__ __launch_bounds__(256) void k_attn_combine(const u16* __restrict__ pctx,
                                                      const float* __restrict__ pm,
                                                      const float* __restrict__ ps,
                                                      u16* __restrict__ ctxb) {
    const int bh = blockIdx.x, qt64 = blockIdx.y + 8;
    const int nseg = (qt64 >> 3) + 1;
    const int t = threadIdx.x, row = t >> 2, h0 = (t & 3) * 16;
    const int tb = (bh * 32 + qt64) * 4;
    float mv[4], sv[4];
#pragma unroll
    for (int s = 0; s < 4; ++s) {
        mv[s] = (s < nseg) ? pm[(tb + s) * 64 + row] : -1e30f;
        sv[s] = (s < nseg) ? ps[(tb + s) * 64 + row] : 0.0f;
    }
    const float mstar = fmaxf(fmaxf(mv[0], mv[1]), fmaxf(mv[2], mv[3]));
    float wv[4], S = 0.0f;
#pragma unroll
    for (int s = 0; s < 4; ++s) {
        wv[s] = __builtin_amdgcn_exp2f(mv[s] - mstar);
        S += wv[s] * sv[s];
    }
    float acc[16] = {};
#pragma unroll
    for (int s = 0; s < 4; ++s) {
        if (s < nseg) {
            const u16* pp = &pctx[(size_t)(tb + s) * 4096 + row * 64 + h0];
            const float wgt = wv[s];
#pragma unroll
            for (int e = 0; e < 2; ++e) {
                s16x8 v = *(const s16x8*)(pp + e * 8);
#pragma unroll
                for (int x = 0; x < 8; ++x)
                    acc[e * 8 + x] += wgt * bf2f((u16)v[x]);
            }
        }
    }
    const float inv = 1.0f / S;
    const int b = bh / 12, h = bh - b * 12;
    u16* op = &ctxb[(size_t)(b * 2048 + qt64 * 64 + row) * 768 + h * 64 + h0];
    s16x8 o0, o1;
#pragma unroll
    for (int x = 0; x < 8; ++x) {
        o0[x] = (short)f2bf(acc[x] * inv);
        o1[x] = (short)f2bf(acc[8 + x] * inv);
    }
    *(s16x8*)op = o0;
    *(s16x8*)(op + 8) = o1;
}

// ---------------- launch ----------------
extern "C" void kernel_launch(void* const* d_in, const int* in_sizes, int n_in,
                              void* d_out, int out_size, void* d_ws, size_t ws_size,
                              hipStream_t stream) {
    (void)in_sizes; (void)n_in; (void)out_size; (void)ws_size;
    const float* x  = (const float*)d_in[0];
    const float* Wq = (const float*)d_in[1];
    const float* bq = (const float*)d_in[2];
    const float* Wk = (const float*)d_in[3];
    const float* bk = (const float*)d_in[4];
    const float* Wv = (const float*)d_in[5];
    const float* bv = (const float*)d_in[6];
    const float* Wo = (const float*)d_in[7];
    const float* bo = (const float*)d_in[8];
    char* ws = (char*)d_ws;
    u16* xb   = (u16*)(ws);               // 4096*768 bf16      = 6291456 B
    u16* wqt  = (u16*)(ws + 6291456);     // 768*768 bf16 (W^T) = 1179648 B
    u16* wkt  = (u16*)(ws + 7471104);
    u16* wvt  = (u16*)(ws + 8650752);
    u16* wot  = (u16*)(ws + 9830400);
    u16* qwv  = (u16*)(ws + 11010048);    // [24][2048][64] bf16 (Q pre-scaled by C2)
    u16* kwv  = (u16*)(ws + 17301504);
    u16* vtw  = (u16*)(ws + 23592960);    // V^T [24][64][2048] bf16
    u16* ctx  = (u16*)(ws + 29884416);    // [4096][768] bf16, ends 36175872
    u16* pctx = (u16*)(ws + 36175872);    // [24][32][4][64][64] bf16 = 25165824 B
    float* pm = (float*)(ws + 61341696);  // [24][32][4][64] f32 = 786432 B
    float* psu= (float*)(ws + 62128128);  // [24][32][4][64] f32 = 786432 B (ends ~63 MB)
    float* out = (float*)d_out;

    k_cvt_bf16<<<1536, 256, 0, stream>>>(x, xb);
    k_transpose_w<<<dim3(24, 24, 4), dim3(32, 8), 0, stream>>>(Wq, Wk, Wv, Wo, wqt, wkt, wvt, wot);
    k_gemm_qkv<<<dim3(36, 32), 256, 0, stream>>>(xb, wqt, wkt, wvt, bq, bk, bv, qwv, kwv, vtw);
    k_attn<<<1920, 128, 0, stream>>>(qwv, kwv, vtw, ctx, pctx, pm, psu);
    k_attn_combine<<<dim3(24, 24), 256, 0, stream>>>(pctx, pm, psu, ctx);
    k_gemm_out<<<dim3(12, 64), 256, 0, stream>>>(ctx, wot, bo, out);
}

// Round 8
// 160.577 us; speedup vs baseline: 1.4116x; 1.0096x over previous
//
#include <hip/hip_runtime.h>
#include <stdint.h>

typedef unsigned short u16;
typedef __attribute__((ext_vector_type(8))) short s16x8;
typedef __attribute__((ext_vector_type(4))) float f32x4;
typedef __attribute__((ext_vector_type(16))) float f32x16;

#define MFMA_BF16(a, b, c) __builtin_amdgcn_mfma_f32_16x16x32_bf16((a), (b), (c), 0, 0, 0)
#define MFMA32(a, b, c) __builtin_amdgcn_mfma_f32_32x32x16_bf16((a), (b), (c), 0, 0, 0)

typedef const __attribute__((address_space(1))) uint32_t* gas1_t;
typedef __attribute__((address_space(3))) uint32_t* las3_t;
#define GLDS16(dst, src) __builtin_amdgcn_global_load_lds((gas1_t)(src), (las3_t)(dst), 16, 0, 0)

static __device__ __forceinline__ u16 f2bf(float f) {
    uint32_t u = __float_as_uint(f);
    u = (u + 0x7fffu + ((u >> 16) & 1u)) >> 16;
    return (u16)u;
}
static __device__ __forceinline__ uint32_t pk2bf(float a, float b) {
    return (uint32_t)f2bf(a) | ((uint32_t)f2bf(b) << 16);
}
static __device__ __forceinline__ float bf2f(u16 h) {
    return __uint_as_float(((uint32_t)h) << 16);
}

// ---------------- prep: x -> bf16  AND  W[k][n] f32 -> Wt[n][k] bf16 (fused) -------
__global__ __launch_bounds__(256) void k_prep(const float* __restrict__ x, u16* __restrict__ xb,
                                              const float* __restrict__ w0, const float* __restrict__ w1,
                                              const float* __restrict__ w2, const float* __restrict__ w3,
                                              u16* __restrict__ t0, u16* __restrict__ t1,
                                              u16* __restrict__ t2, u16* __restrict__ t3) {
    __shared__ float tile[32][33];
    const int bid = blockIdx.x, t = threadIdx.x;
    if (bid < 1536) {
        const int i = (bid * 256 + t) * 8;
        f32x4 a = *(const f32x4*)(x + i);
        f32x4 b = *(const f32x4*)(x + i + 4);
        s16x8 r;
        r[0] = (short)f2bf(a[0]); r[1] = (short)f2bf(a[1]);
        r[2] = (short)f2bf(a[2]); r[3] = (short)f2bf(a[3]);
        r[4] = (short)f2bf(b[0]); r[5] = (short)f2bf(b[1]);
        r[6] = (short)f2bf(b[2]); r[7] = (short)f2bf(b[3]);
        *(s16x8*)(xb + i) = r;
        return;
    }
    const int u = bid - 1536;
    const int z = u / 576, r2 = u - z * 576;
    const float* W; u16* T;
    switch (z) {
        case 0:  W = w0; T = t0; break;
        case 1:  W = w1; T = t1; break;
        case 2:  W = w2; T = t2; break;
        default: W = w3; T = t3; break;
    }
    const int n0 = (r2 % 24) * 32, k0 = (r2 / 24) * 32;
    const int tx = t & 31, ty = t >> 5;
#pragma unroll
    for (int i = 0; i < 4; ++i)
        tile[ty + 8 * i][tx] = W[(size_t)(k0 + ty + 8 * i) * 768 + n0 + tx];
    __syncthreads();
#pragma unroll
    for (int i = 0; i < 4; ++i)
        T[(size_t)(n0 + ty + 8 * i) * 768 + k0 + tx] = f2bf(tile[tx][ty + 8 * i]);
}

// ---------------- fused QKV GEMM: 128x64 tiles, XCD-chunked block swizzle ----------
// 1152 blocks: swz=(cid%8)*144+cid/8; sel=swz%36/12, head=swz%12, m-tile=swz/36.
__global__ __launch_bounds__(256) void k_gemm_qkv(
        const u16* __restrict__ A,
        const u16* __restrict__ btq, const u16* __restrict__ btk, const u16* __restrict__ btv,
        const float* __restrict__ bq, const float* __restrict__ bk, const float* __restrict__ bv,
        u16* __restrict__ outq, u16* __restrict__ outk, u16* __restrict__ outv) {
    __shared__ u16 lA[128 * 64];
    __shared__ u16 lB[64 * 64];
    const int cid = blockIdx.x;
    const int swz = (cid & 7) * 144 + (cid >> 3);
    const int sx = swz % 36, by = swz / 36;
    const int sel = sx / 12, nb = sx - sel * 12;
    const u16* Bt; const float* bias;
    if (sel == 0)      { Bt = btq; bias = bq; }
    else if (sel == 1) { Bt = btk; bias = bk; }
    else               { Bt = btv; bias = bv; }
    const int t = threadIdx.x, lane = t & 63, w = t >> 6;
    const int wr = w >> 1, wc = w & 1;
    const int c = lane & 15, g = lane >> 4;
    const int m0 = by * 128, n0 = nb * 64;
    f32x4 acc[4][2] = {};
    const int lr = lane >> 3, lg = lane & 7;
    const int swz8 = 8 * (lg ^ lr);
    const u16* gA = A  + (size_t)(m0 + w * 8 + lr) * 768 + swz8;
    const u16* gB = Bt + (size_t)(n0 + w * 8 + lr) * 768 + swz8;
    for (int kb = 0; kb < 768; kb += 64) {
#pragma unroll
        for (int j = 0; j < 4; ++j)
            GLDS16(&lA[j * 2048 + w * 512], gA + (size_t)j * 32 * 768 + kb);
#pragma unroll
        for (int j = 0; j < 2; ++j)
            GLDS16(&lB[j * 2048 + w * 512], gB + (size_t)j * 32 * 768 + kb);
        __syncthreads();
#pragma unroll
        for (int kh = 0; kh < 2; ++kh) {
            s16x8 af[4], bfr[2];
            const int gg = kh * 4 + g;
#pragma unroll
            for (int i = 0; i < 4; ++i) {
                const int ra = wr * 64 + i * 16 + c;
                af[i] = *(const s16x8*)&lA[ra * 64 + 8 * (gg ^ (ra & 7))];
            }
#pragma unroll
            for (int j = 0; j < 2; ++j) {
                const int rb = wc * 32 + j * 16 + c;
                bfr[j] = *(const s16x8*)&lB[rb * 64 + 8 * (gg ^ (rb & 7))];
            }
#pragma unroll
            for (int i = 0; i < 4; ++i)
#pragma unroll
                for (int j = 0; j < 2; ++j)
                    acc[i][j] = MFMA_BF16(af[i], bfr[j], acc[i][j]);
        }
        __syncthreads();
    }
    const float C2 = 0.18033688011112042f;  // (1/8)*log2(e), folded into Q
    const int h = nb;
    if (sel < 2) {
        u16* outp = (sel == 0) ? outq : outk;
        const float osc = (sel == 0) ? C2 : 1.0f;
#pragma unroll
        for (int i = 0; i < 4; ++i)
#pragma unroll
            for (int j = 0; j < 2; ++j) {
                const int hd = wc * 32 + j * 16 + c;
                const float bvv = bias[n0 + hd];
#pragma unroll
                for (int rr = 0; rr < 4; ++rr) {
                    const int m = m0 + wr * 64 + i * 16 + g * 4 + rr;
                    const int b = m >> 11, s = m & 2047;
                    outp[(((size_t)(b * 12 + h) * 2048 + s) << 6) + hd] =
                        f2bf((acc[i][j][rr] + bvv) * osc);
                }
            }
    } else {
#pragma unroll
        for (int i = 0; i < 4; ++i)
#pragma unroll
            for (int j = 0; j < 2; ++j) {
                const int hd = wc * 32 + j * 16 + c;
                const float bvv = bias[n0 + hd];
                const int m = m0 + wr * 64 + i * 16 + g * 4;
                const int b = m >> 11, s = m & 2047;
                uint64_t pk = (uint64_t)pk2bf(acc[i][j][0] + bvv, acc[i][j][1] + bvv) |
                              ((uint64_t)pk2bf(acc[i][j][2] + bvv, acc[i][j][3] + bvv) << 32);
                *(uint64_t*)&outv[((size_t)(b * 12 + h) * 64 + hd) * 2048 + s] = pk;
            }
    }
}

// ---------------- out-projection GEMM: 64x64, XCD-chunked swizzle ----------------
__global__ __launch_bounds__(256) void k_gemm_out(const u16* __restrict__ A,
                                                  const u16* __restrict__ Bt,
                                                  const float* __restrict__ bias,
                                                  float* __restrict__ out) {
    __shared__ u16 lA[64 * 64];
    __shared__ u16 lB[64 * 64];
    const int cid = blockIdx.x;
    const int swz = (cid & 7) * 96 + (cid >> 3);
    const int bx = swz % 12, by = swz / 12;
    const int t = threadIdx.x;
    const int lane = t & 63, w = t >> 6;
    const int wr = w >> 1, wc = w & 1;
    const int c = lane & 15, g = lane >> 4;
    const int m0 = by * 64, n0 = bx * 64;
    f32x4 acc[2][2] = {};
    const int lr = lane >> 3, lq = lane & 7;
    const int sq = (lq ^ lr) * 8;
    const u16* gA0 = A  + (size_t)(m0 + w * 16 + lr) * 768 + sq;
    const u16* gA1 = gA0 + 8 * 768;
    const u16* gB0 = Bt + (size_t)(n0 + w * 16 + lr) * 768 + sq;
    const u16* gB1 = gB0 + 8 * 768;
    u16* dA0 = &lA[w * 1024];
    u16* dA1 = &lA[w * 1024 + 512];
    u16* dB0 = &lB[w * 1024];
    u16* dB1 = &lB[w * 1024 + 512];
    for (int kb = 0; kb < 768; kb += 64) {
        GLDS16(dA0, gA0 + kb); GLDS16(dA1, gA1 + kb);
        GLDS16(dB0, gB0 + kb); GLDS16(dB1, gB1 + kb);
        __syncthreads();
#pragma unroll
        for (int st = 0; st < 2; ++st) {
            s16x8 af[2], bf[2];
            const int col = st * 32 + g * 8;
#pragma unroll
            for (int i = 0; i < 2; ++i) {
                int ra = wr * 32 + i * 16 + c;
                af[i] = *(const s16x8*)&lA[ra * 64 + (col ^ ((ra & 7) << 3))];
                int rb = wc * 32 + i * 16 + c;
                bf[i] = *(const s16x8*)&lB[rb * 64 + (col ^ ((rb & 7) << 3))];
            }
#pragma unroll
            for (int i = 0; i < 2; ++i)
#pragma unroll
                for (int j = 0; j < 2; ++j)
                    acc[i][j] = MFMA_BF16(af[i], bf[j], acc[i][j]);
        }
        __syncthreads();
    }
#pragma unroll
    for (int i = 0; i < 2; ++i)
#pragma unroll
        for (int j = 0; j < 2; ++j) {
            const int n = n0 + wc * 32 + j * 16 + c;
            const float bvv = bias[n];
#pragma unroll
            for (int rr = 0; rr < 4; ++rr) {
                const int m = m0 + wr * 32 + i * 16 + g * 4 + rr;
                out[(size_t)m * 768 + n] = acc[i][j][rr] + bvv;
            }
        }
}

// ---------------- causal flash attention: split-K, 4 waves x 32 q-rows ----------------
// Block = 128-row q-tile (4 waves), one 512-key segment (<=8 chunks of 64 keys).
// 40 slots x 24 bh = 960 blocks, heavy slots first; bh permuted so each XCD owns 3 heads.
__device__ static const signed char SLOT_QT[40] = {
    15,15,15,15, 14,14,14,14, 13,13,13,13, 12,12,12,12,
    11,11,11, 10,10,10, 9,9,9, 8,8,8, 7,7, 6,6, 5,5, 4,4, 3, 2, 1, 0};
__device__ static const signed char SLOT_SEG[40] = {
    0,1,2,3, 0,1,2,3, 0,1,2,3, 0,1,2,3,
    0,1,2, 0,1,2, 0,1,2, 0,1,2, 0,1, 0,1, 0,1, 0,1, 0, 0, 0, 0};

__global__ __launch_bounds__(256) void k_attn(const u16* __restrict__ qw,
                                              const u16* __restrict__ kw,
                                              const u16* __restrict__ vt,
                                              u16* __restrict__ ctxb,
                                              u16* __restrict__ pctx,
                                              float* __restrict__ pm,
                                              float* __restrict__ ps) {
    __shared__ u16 lK[2][64 * 64];   // [key][hd], XOR-swizzled (granule ^ row&7)
    __shared__ u16 lV[2][64 * 64];   // V^T [hd][key], same swizzle
    const int bid = blockIdx.x;
    const int slot = bid / 24, j24 = bid - slot * 24;
    const int bh = (j24 & 7) * 3 + (j24 >> 3);   // XCD j24&7 always sees heads 3x..3x+2
    const int qt = SLOT_QT[slot], seg = SLOT_SEG[slot];
    const int nseg = (2 * (qt + 1) + 7) >> 3;
    const int ch0 = seg * 8;
    const int rem = 2 * (qt + 1) - ch0;
    const int nch = rem < 8 ? rem : 8;
    const int t = threadIdx.x, lane = t & 63, w = t >> 6;   // w in 0..3
    const int l31 = lane & 31, hi = lane >> 5;
    const int q0w = qt * 128 + w * 32;
    const u16* qp = qw + (size_t)bh * 2048 * 64;
    const u16* kp = kw + (size_t)bh * 2048 * 64;
    const u16* vp = vt + (size_t)bh * 64 * 2048;
    s16x8 qf[4];
#pragma unroll
    for (int dk = 0; dk < 4; ++dk)
        qf[dk] = *(const s16x8*)&qp[(size_t)(q0w + l31) * 64 + dk * 16 + hi * 8];
    asm volatile("s_waitcnt vmcnt(0)" ::: "memory");
    // staging: wave w covers K/V rows [w*16, w*16+16) -> 4 GLDS16 per chunk per wave
    const int lr = lane >> 3, lg = lane & 7;
    const int swz8 = 8 * (lg ^ lr);
    const u16* kpb = kp + (size_t)(w * 16 + lr) * 64 + swz8;
    const u16* vpb = vp + (size_t)(w * 16 + lr) * 2048 + swz8;
    const int lastq = q0w + 31;
    f32x16 ct[2] = {};               // ctx^T: col=q, rows=hd
    float m2 = -1e30f, ssum = 0.0f;
#define STAGE(bf, ch)                                                          \
    {                                                                          \
        const u16* ks_ = kpb + (size_t)(ch) * 4096;                            \
        GLDS16(&lK[bf][(w * 16) * 64], ks_);                                   \
        GLDS16(&lK[bf][(w * 16 + 8) * 64], ks_ + 8 * 64);                      \
        const u16* vs_ = vpb + (size_t)(ch) * 64;                              \
        GLDS16(&lV[bf][(w * 16) * 64], vs_);                                   \
        GLDS16(&lV[bf][(w * 16 + 8) * 64], vs_ + 8 * 2048);                    \
    }
    STAGE(0, ch0);
    for (int ci = 0; ci < nch; ++ci) {
        const int bf = ci & 1, Kc = (ch0 + ci) * 64;
        if (ci + 1 < nch) {
            STAGE(bf ^ 1, ch0 + ci + 1);
            asm volatile("s_waitcnt vmcnt(4)" ::: "memory");
        } else {
            asm volatile("s_waitcnt vmcnt(0)" ::: "memory");
        }
        __builtin_amdgcn_sched_barrier(0);
        __builtin_amdgcn_s_barrier();
        if (Kc <= lastq) {           // wave-uniform causal skip
            f32x16 st[2] = {};
            __builtin_amdgcn_s_setprio(1);
#pragma unroll
            for (int dk = 0; dk < 4; ++dk) {
                const int gr = dk * 2 + hi;
                const int r0 = l31, r1 = 32 + l31;
                s16x8 kf0 = *(const s16x8*)&lK[bf][r0 * 64 + 8 * (gr ^ (r0 & 7))];
                s16x8 kf1 = *(const s16x8*)&lK[bf][r1 * 64 + 8 * (gr ^ (r1 & 7))];
                st[0] = MFMA32(kf0, qf[dk], st[0]);
                st[1] = MFMA32(kf1, qf[dk], st[1]);
            }
            __builtin_amdgcn_s_setprio(0);
            const int qg = q0w + l31;
            float tv[32];
            if (Kc + 63 <= q0w) {
#pragma unroll
                for (int j = 0; j < 16; ++j) { tv[j] = st[0][j]; tv[16 + j] = st[1][j]; }
            } else {
                const int kb = Kc + 4 * hi;
#pragma unroll
                for (int j = 0; j < 16; ++j) {
                    const int kloc = (j & 3) + 8 * (j >> 2);
                    tv[j]      = (kb + kloc      <= qg) ? st[0][j] : -1e30f;
                    tv[16 + j] = (kb + kloc + 32 <= qg) ? st[1][j] : -1e30f;
                }
            }
            // ---- tree max ----
            float x16[16], x8[8], x4[4];
#pragma unroll
            for (int j = 0; j < 16; ++j) x16[j] = fmaxf(tv[j], tv[j + 16]);
#pragma unroll
            for (int j = 0; j < 8; ++j) x8[j] = fmaxf(x16[j], x16[j + 8]);
#pragma unroll
            for (int j = 0; j < 4; ++j) x4[j] = fmaxf(x8[j], x8[j + 4]);
            const float mt = fmaxf(fmaxf(x4[0], x4[1]), fmaxf(x4[2], x4[3]));
            if (!__all(mt <= m2 + 8.0f)) {
                float mq = fmaxf(mt, __shfl_xor(mt, 32));
                const float mnew = fmaxf(m2, mq);
                const float fac = __builtin_amdgcn_exp2f(m2 - mnew);
                ssum *= fac;
#pragma unroll
                for (int j = 0; j < 16; ++j) { ct[0][j] *= fac; ct[1][j] *= fac; }
                m2 = mnew;
            }
            float p[32];
#pragma unroll
            for (int j = 0; j < 32; ++j) p[j] = __builtin_amdgcn_exp2f(tv[j] - m2);
            // ---- tree sum ----
            float y16[16], y8[8], y4[4];
#pragma unroll
            for (int j = 0; j < 16; ++j) y16[j] = p[j] + p[j + 16];
#pragma unroll
            for (int j = 0; j < 8; ++j) y8[j] = y16[j] + y16[j + 8];
#pragma unroll
            for (int j = 0; j < 4; ++j) y4[j] = y8[j] + y8[j + 4];
            ssum += (y4[0] + y4[1]) + (y4[2] + y4[3]);
            // ---- P -> bf16 B-frags via cvt_pk + permlane32_swap; PV ----
#pragma unroll
            for (int kt = 0; kt < 2; ++kt) {
                uint32_t pcv[8];
#pragma unroll
                for (int x = 0; x < 8; ++x) {
                    const int j = kt * 16 + 4 * (x >> 1) + 2 * (x & 1);
                    asm volatile("v_cvt_pk_bf16_f32 %0, %1, %2"
                                 : "=v"(pcv[x]) : "v"(p[j]), "v"(p[j + 1]));
                }
#pragma unroll
                for (int kl = 0; kl < 2; ++kl) {
                    uint32_t a0 = pcv[4 * kl],     b0 = pcv[4 * kl + 2];
                    uint32_t a1 = pcv[4 * kl + 1], b1 = pcv[4 * kl + 3];
                    asm volatile("v_permlane32_swap_b32 %0, %1" : "+v"(a0), "+v"(b0));
                    asm volatile("v_permlane32_swap_b32 %0, %1" : "+v"(a1), "+v"(b1));
                    union { uint32_t u[4]; s16x8 v; } pf;
                    pf.u[0] = a0; pf.u[1] = a1; pf.u[2] = b0; pf.u[3] = b1;
                    const int gr = (kt * 2 + kl) * 2 + hi;
                    const int rv0 = l31, rv1 = 32 + l31;
                    s16x8 vf0 = *(const s16x8*)&lV[bf][rv0 * 64 + 8 * (gr ^ (rv0 & 7))];
                    s16x8 vf1 = *(const s16x8*)&lV[bf][rv1 * 64 + 8 * (gr ^ (rv1 & 7))];
                    __builtin_amdgcn_s_setprio(1);
                    ct[0] = MFMA32(vf0, pf.v, ct[0]);
                    ct[1] = MFMA32(vf1, pf.v, ct[1]);
                    __builtin_amdgcn_s_setprio(0);
                }
            }
        }
        __builtin_amdgcn_s_barrier();
    }
    if (nseg == 1) {
        // direct write (tile fully computed by this block)
        ssum += __shfl_xor(ssum, 32);
        const float inv = 1.0f / ssum;
        const int b = bh / 12, h = bh - b * 12;
        const size_t base = (size_t)(b * 2048 + q0w + l31) * 768 + h * 64;
#pragma unroll
        for (int ht = 0; ht < 2; ++ht)
#pragma unroll
            for (int a = 0; a < 4; ++a) {
                const int hd = ht * 32 + 8 * a + 4 * hi;
                uint64_t pk = (uint64_t)pk2bf(ct[ht][4 * a] * inv, ct[ht][4 * a + 1] * inv) |
                              ((uint64_t)pk2bf(ct[ht][4 * a + 2] * inv, ct[ht][4 * a + 3] * inv) << 32);
                *(uint64_t*)&ctxb[base + hd] = pk;
            }
    } else {
        // partial write: unnormalized bf16 ctx + per-row (m, ssum)
        const float srow = ssum + __shfl_xor(ssum, 32);
        const int ti = (bh * 16 + qt) * 4 + seg;
        const int row = w * 32 + l31;
        u16* pp = &pctx[(size_t)ti * 8192 + row * 64];
#pragma unroll
        for (int ht = 0; ht < 2; ++ht)
#pragma unroll
            for (int a = 0; a < 4; ++a) {
                const int hd = ht * 32 + 8 * a + 4 * hi;
                uint64_t pk = (uint64_t)pk2bf(ct[ht][4 * a], ct[ht][4 * a + 1]) |
                              ((uint64_t)pk2bf(ct[ht][4 * a + 2], ct[ht][4 * a + 3]) << 32);
                *(uint64_t*)&pp[hd] = pk;
            }
        if (hi == 0) {
            pm[ti * 128 + row] = m2;
            ps[ti * 128 + row] = srow;
        }
    }
#undef STAGE
}

// ---------------- split-K combine: merge <=4 segments per 128-row tile ----------------
// grid (24 bh, 12 tiles [qt=4..15]) x 256 thr x 2 iters; unit = 1 row x 16 hd.
__global__ __launch_bounds__(256) void k_attn_combine(const u16* __restrict__ pctx,
                                                      const float* __restrict__ pm,
                                                      const float* __restrict__ ps,
                                                      u16* __restrict__ ctxb) {
    const int bh = blockIdx.x, qt = blockIdx.y + 4;
    const int nseg = (2 * (qt + 1) + 7) >> 3;
    const int tb = (bh * 16 + qt) * 4;
    const int b = bh / 12, h = bh - b * 12;
#pragma unroll
    for (int it = 0; it < 2; ++it) {
        const int u = threadIdx.x + it * 256;
        const int row = u >> 2, h0 = (u & 3) * 16;
        float mv[4], sv[4];
#pragma unroll
        for (int s = 0; s < 4; ++s) {
            mv[s] = (s < nseg) ? pm[(tb + s) * 128 + row] : -1e30f;
            sv[s] = (s < nseg) ? ps[(tb + s) * 128 + row] : 0.0f;
        }
        const float mstar = fmaxf(fmaxf(mv[0], mv[1]), fmaxf(mv[2], mv[3]));
        float wv[4], S = 0.0f;
#pragma unroll
        for (int s = 0; s < 4; ++s) {
            wv[s] = __builtin_amdgcn_exp2f(mv[s] - mstar);
            S += wv[s] * sv[s];
        }
        float acc[16] = {};
#pragma unroll
        for (int s = 0; s < 4; ++s) {
            if (s < nseg) {
                const u16* pp = &pctx[(size_t)(tb + s) * 8192 + row * 64 + h0];
                const float wgt = wv[s];
#pragma unroll
                for (int e = 0; e < 2; ++e) {
                    s16x8 v = *(const s16x8*)(pp + e * 8);
#pragma unroll
                    for (int x = 0; x < 8; ++x)
                        acc[e * 8 + x] += wgt * bf2f((u16)v[x]);
                }
            }
        }
        const float inv = 1.0f / S;
        u16* op = &ctxb[(size_t)(b * 2048 + qt * 128 + row) * 768 + h * 64 + h0];
        s16x8 o0, o1;
#pragma unroll
        for (int x = 0; x < 8; ++x) {
            o0[x] = (short)f2bf(acc[x] * inv);
            o1[x] = (short)f2bf(acc[8 + x] * inv);
        }
        *(s16x8*)op = o0;
        *(s16x8*)(op + 8) = o1;
    }
}

// ---------------- launch ----------------
extern "C" void kernel_launch(void* const* d_in, const int* in_sizes, int n_in,
                              void* d_out, int out_size, void* d_ws, size_t ws_size,
                              hipStream_t stream) {
    (void)in_sizes; (void)n_in; (void)out_size; (void)ws_size;
    const float* x  = (const float*)d_in[0];
    const float* Wq = (const float*)d_in[1];
    const float* bq = (const float*)d_in[2];
    const float* Wk = (const float*)d_in[3];
    const float* bk = (const float*)d_in[4];
    const float* Wv = (const float*)d_in[5];
    const float* bv = (const float*)d_in[6];
    const float* Wo = (const float*)d_in[7];
    const float* bo = (const float*)d_in[8];
    char* ws = (char*)d_ws;
    u16* xb   = (u16*)(ws);               // 4096*768 bf16      = 6291456 B
    u16* wqt  = (u16*)(ws + 6291456);     // 768*768 bf16 (W^T) = 1179648 B
    u16* wkt  = (u16*)(ws + 7471104);
    u16* wvt  = (u16*)(ws + 8650752);
    u16* wot  = (u16*)(ws + 9830400);
    u16* qwv  = (u16*)(ws + 11010048);    // [24][2048][64] bf16 (Q pre-scaled by C2)
    u16* kwv  = (u16*)(ws + 17301504);
    u16* vtw  = (u16*)(ws + 23592960);    // V^T [24][64][2048] bf16
    u16* ctx  = (u16*)(ws + 29884416);    // [4096][768] bf16, ends 36175872
    u16* pctx = (u16*)(ws + 36175872);    // [24][16][4][128][64] bf16 = 25165824 B
    float* pm = (float*)(ws + 61341696);  // [24][16][4][128] f32 = 786432 B
    float* psu= (float*)(ws + 62128128);  // [24][16][4][128] f32 = 786432 B
    float* out = (float*)d_out;

    k_prep<<<3840, 256, 0, stream>>>(x, xb, Wq, Wk, Wv, Wo, wqt, wkt, wvt, wot);
    k_gemm_qkv<<<1152, 256, 0, stream>>>(xb, wqt, wkt, wvt, bq, bk, bv, qwv, kwv, vtw);
    k_attn<<<960, 256, 0, stream>>>(qwv, kwv, vtw, ctx, pctx, pm, psu);
    k_attn_combine<<<dim3(24, 12), 256, 0, stream>>>(pctx, pm, psu, ctx);
    k_gemm_out<<<768, 256, 0, stream>>>(ctx, wot, bo, out);
}